// Round 1
// baseline (172.118 us; speedup 1.0000x reference)
//
#include <hip/hip_runtime.h>
#include <hip/hip_bf16.h>

#define NB 4096
#define DD 768

typedef __bf16 bf16x8 __attribute__((ext_vector_type(8)));
typedef float f32x4 __attribute__((ext_vector_type(4)));

// ---------------- normalize: f32 row -> bf16 L2-normalized row ----------------
__global__ __launch_bounds__(256) void normalize_kernel(
    const float* __restrict__ vf, const float* __restrict__ tf,
    __hip_bfloat16* __restrict__ vhat, __hip_bfloat16* __restrict__ that_)
{
    int row = blockIdx.x;
    const float* src;
    __hip_bfloat16* dst;
    if (row < NB) { src = vf + (size_t)row * DD; dst = vhat + (size_t)row * DD; }
    else          { src = tf + (size_t)(row - NB) * DD; dst = that_ + (size_t)(row - NB) * DD; }
    int t = threadIdx.x;
    float x0 = src[t], x1 = src[t + 256], x2 = src[t + 512];
    float s = x0 * x0 + x1 * x1 + x2 * x2;
    #pragma unroll
    for (int off = 32; off > 0; off >>= 1) s += __shfl_down(s, off, 64);
    __shared__ float wsum[4];
    int wid = t >> 6, lane = t & 63;
    if (lane == 0) wsum[wid] = s;
    __syncthreads();
    float tot = wsum[0] + wsum[1] + wsum[2] + wsum[3];
    float scale = 1.0f / sqrtf(tot);
    dst[t]       = __float2bfloat16(x0 * scale);
    dst[t + 256] = __float2bfloat16(x1 * scale);
    dst[t + 512] = __float2bfloat16(x2 * scale);
}

// ---------------- cnt[i] = #{j : ids[j]==ids[i]} (includes self) ----------------
__global__ __launch_bounds__(256) void cnt_kernel(
    const int* __restrict__ ids, float* __restrict__ cntf, int* __restrict__ num_pos)
{
    __shared__ int sh[512];
    int i = blockIdx.x * 256 + threadIdx.x;
    int my = ids[i];
    int c = 0;
    for (int base = 0; base < NB; base += 512) {
        sh[threadIdx.x]       = ids[base + threadIdx.x];
        sh[threadIdx.x + 256] = ids[base + threadIdx.x + 256];
        __syncthreads();
        #pragma unroll 16
        for (int j = 0; j < 512; ++j) c += (sh[j] == my);
        __syncthreads();
    }
    cntf[i] = (float)c;
    atomicAdd(num_pos, c);
}

// ---------------- GEMM: sim tile = vhat(128 rows) x that(128 rows)^T ----------------
// MODE 0: accumulate {total_sum, S_mf(incl diag), trace} into scal[0..2]
// MODE 1: accumulate row/col sums of exp((sim-1)/temp) into rs[], cs[]
template <int MODE>
__global__ __launch_bounds__(256) void gemm_kernel(
    const __hip_bfloat16* __restrict__ vhat, const __hip_bfloat16* __restrict__ that_,
    const int* __restrict__ ids, float* __restrict__ scal,
    float* __restrict__ rs, float* __restrict__ cs)
{
    __shared__ __hip_bfloat16 As[128 * 32];
    __shared__ __hip_bfloat16 Bs[128 * 32];
    __shared__ int   idr[128], idc[128];
    __shared__ float red[12];
    __shared__ float rs_l[128], cs_l[128];

    int bx = blockIdx.x & 31, by = blockIdx.x >> 5;
    int rowBase = by * 128, colBase = bx * 128;
    int t = threadIdx.x;
    int wid = t >> 6, lane = t & 63;
    int wr = wid >> 1, wc = wid & 1;

    if (MODE == 0) {
        if (t < 128) { idr[t] = ids[rowBase + t]; idc[t] = ids[colBase + t]; }
    } else {
        if (t < 128) { rs_l[t] = 0.0f; cs_l[t] = 0.0f; }
    }

    f32x4 acc[4][4];
    #pragma unroll
    for (int m = 0; m < 4; ++m)
        #pragma unroll
        for (int n = 0; n < 4; ++n) acc[m][n] = (f32x4){0.f, 0.f, 0.f, 0.f};

    int srow = lane >> 2;          // 0..15 (row within 16-row chunk)
    int scol = (lane & 3) * 8;     // bf16 offset within BK=32
    const __hip_bfloat16* aSrc = vhat  + (size_t)rowBase * DD;
    const __hip_bfloat16* bSrc = that_ + (size_t)colBase * DD;

    int fr = lane & 15;            // fragment row/col index
    int kg = (lane >> 4) * 8;      // k-group offset

    for (int k0 = 0; k0 < DD; k0 += 32) {
        __syncthreads();  // previous-iter LDS reads done (also covers idr/rs_l init)
        #pragma unroll
        for (int p = 0; p < 2; ++p) {
            int r = p * 64 + wid * 16 + srow;
            const __hip_bfloat16* ga = aSrc + (size_t)r * DD + k0 + scol;
            __builtin_amdgcn_global_load_lds(
                (const __attribute__((address_space(1))) void*)ga,
                (__attribute__((address_space(3))) void*)(As + (p * 64 + wid * 16) * 32),
                16, 0, 0);
            const __hip_bfloat16* gb = bSrc + (size_t)r * DD + k0 + scol;
            __builtin_amdgcn_global_load_lds(
                (const __attribute__((address_space(1))) void*)gb,
                (__attribute__((address_space(3))) void*)(Bs + (p * 64 + wid * 16) * 32),
                16, 0, 0);
        }
        __syncthreads();  // staging complete (vmcnt drained by barrier semantics)

        bf16x8 a[4], b[4];
        #pragma unroll
        for (int m = 0; m < 4; ++m)
            a[m] = *(const bf16x8*)(As + (wr * 64 + m * 16 + fr) * 32 + kg);
        #pragma unroll
        for (int n = 0; n < 4; ++n)
            b[n] = *(const bf16x8*)(Bs + (wc * 64 + n * 16 + fr) * 32 + kg);
        #pragma unroll
        for (int m = 0; m < 4; ++m)
            #pragma unroll
            for (int n = 0; n < 4; ++n)
                acc[m][n] = __builtin_amdgcn_mfma_f32_16x16x32_bf16(a[m], b[n], acc[m][n], 0, 0, 0);
    }

    int g = lane >> 4;  // C/D layout: col = lane&15, row = g*4 + reg   [m89-verified]

    if (MODE == 0) {
        float tsum = 0.f, msum = 0.f, dsum = 0.f;
        #pragma unroll
        for (int m = 0; m < 4; ++m) {
            int rl = wr * 64 + m * 16 + g * 4;
            #pragma unroll
            for (int n = 0; n < 4; ++n) {
                int cl = wc * 64 + n * 16 + fr;
                int colId = idc[cl];
                int gj = colBase + cl;
                #pragma unroll
                for (int r = 0; r < 4; ++r) {
                    float val = acc[m][n][r];
                    tsum += val;
                    if (idr[rl + r] == colId) msum += val;
                    if (rowBase + rl + r == gj) dsum += val;
                }
            }
        }
        #pragma unroll
        for (int off = 32; off > 0; off >>= 1) {
            tsum += __shfl_down(tsum, off, 64);
            msum += __shfl_down(msum, off, 64);
            dsum += __shfl_down(dsum, off, 64);
        }
        if (lane == 0) { red[wid] = tsum; red[4 + wid] = msum; red[8 + wid] = dsum; }
        __syncthreads();
        if (t == 0) {
            atomicAdd(&scal[0], red[0] + red[1] + red[2] + red[3]);
            atomicAdd(&scal[1], red[4] + red[5] + red[6] + red[7]);
            atomicAdd(&scal[2], red[8] + red[9] + red[10] + red[11]);
        }
    } else {
        float invT = scal[4];
        // overwrite acc with exp((sim-1)/temp)
        #pragma unroll
        for (int m = 0; m < 4; ++m)
            #pragma unroll
            for (int n = 0; n < 4; ++n)
                #pragma unroll
                for (int r = 0; r < 4; ++r)
                    acc[m][n][r] = __expf((acc[m][n][r] - 1.0f) * invT);
        // row partial sums: sum over cols (16 lanes sharing same g) and n-frags
        #pragma unroll
        for (int m = 0; m < 4; ++m) {
            #pragma unroll
            for (int r = 0; r < 4; ++r) {
                float rp = 0.f;
                #pragma unroll
                for (int n = 0; n < 4; ++n) rp += acc[m][n][r];
                rp += __shfl_xor(rp, 1, 64);
                rp += __shfl_xor(rp, 2, 64);
                rp += __shfl_xor(rp, 4, 64);
                rp += __shfl_xor(rp, 8, 64);
                if (fr == 0) atomicAdd(&rs_l[wr * 64 + m * 16 + g * 4 + r], rp);
            }
        }
        // col partial sums: sum over rows (4 g-groups) and m-frags, r
        #pragma unroll
        for (int n = 0; n < 4; ++n) {
            float cp = 0.f;
            #pragma unroll
            for (int m = 0; m < 4; ++m)
                #pragma unroll
                for (int r = 0; r < 4; ++r) cp += acc[m][n][r];
            cp += __shfl_xor(cp, 16, 64);
            cp += __shfl_xor(cp, 32, 64);
            if (g == 0) atomicAdd(&cs_l[wc * 64 + n * 16 + fr], cp);
        }
        __syncthreads();
        if (t < 128)      atomicAdd(&rs[rowBase + t], rs_l[t]);
        else if (t < 256) atomicAdd(&cs[colBase + t - 128], cs_l[t - 128]);
    }
}

// ---------------- temp from global stats ----------------
__global__ void temp_kernel(float* scal, const int* num_pos_i)
{
    float total = scal[0], mf = scal[1], trace = scal[2];
    float np = (float)(*num_pos_i);
    float pos_cnt = np - (float)NB;
    float neg_cnt = (float)NB * (float)NB - np;
    float pos_mean = (mf - trace) / fmaxf(1.0f, pos_cnt);
    float neg_mean = (total - mf) / fmaxf(1.0f, neg_cnt);
    float sep = pos_mean - neg_mean;
    float temp = 0.07f * (0.8f + 0.4f * expf(-2.0f * sep));
    temp = fminf(fmaxf(temp, 0.04f), 0.2f);
    scal[3] = temp;
    scal[4] = 1.0f / temp;
}

// ---------------- final loss ----------------
__global__ __launch_bounds__(256) void final_kernel(
    const float* __restrict__ scal, const float* __restrict__ rs, const float* __restrict__ cs,
    const float* __restrict__ cntf, float* __restrict__ out)
{
    int t = threadIdx.x;
    float a = 0.0f, npl = 0.0f;
    for (int i = t; i < NB; i += 256) {
        float c = cntf[i];
        a += c * (logf(rs[i]) + logf(cs[i]));
        npl += c;
    }
    #pragma unroll
    for (int off = 32; off > 0; off >>= 1) {
        a += __shfl_down(a, off, 64);
        npl += __shfl_down(npl, off, 64);
    }
    __shared__ float ra[4], rn[4];
    int wid = t >> 6, lane = t & 63;
    if (lane == 0) { ra[wid] = a; rn[wid] = npl; }
    __syncthreads();
    if (t == 0) {
        float A  = ra[0] + ra[1] + ra[2] + ra[3];
        float np = rn[0] + rn[1] + rn[2] + rn[3];
        float invT = scal[4], mf = scal[1];
        // lse_row[i] = 1/temp + log(rs[i]);  same for cols.
        // v2t + t2v = sum cnt*(lse_r + lse_c) - 2*mf/temp
        float loss = (A + 2.0f * invT * (np - mf)) / (2.0f * np);
        out[0] = loss;
    }
}

extern "C" void kernel_launch(void* const* d_in, const int* in_sizes, int n_in,
                              void* d_out, int out_size, void* d_ws, size_t ws_size,
                              hipStream_t stream)
{
    const float* vf  = (const float*)d_in[0];
    const float* tf  = (const float*)d_in[1];
    const int*   ids = (const int*)d_in[2];

    float* ws_f = (float*)d_ws;
    float* scal = ws_f;                 // [0]=total [1]=S_mf [2]=trace [3]=temp [4]=1/temp [5]=num_pos(int)
    float* rs   = ws_f + 16;            // 4096
    float* cs   = ws_f + 16 + 4096;     // 4096
    float* cntf = ws_f + 16 + 8192;     // 4096 (fully overwritten, no zeroing needed)
    __hip_bfloat16* vhat  = (__hip_bfloat16*)((char*)d_ws + 65536);
    __hip_bfloat16* that_ = vhat + (size_t)NB * DD;

    // zero scal + rs + cs (re-zeroed on every call: graph replays accumulate via atomics)
    hipMemsetAsync(d_ws, 0, (16 + 8192) * sizeof(float), stream);

    normalize_kernel<<<2 * NB, 256, 0, stream>>>(vf, tf, vhat, that_);
    cnt_kernel<<<NB / 256, 256, 0, stream>>>(ids, cntf, (int*)(scal + 5));
    gemm_kernel<0><<<1024, 256, 0, stream>>>(vhat, that_, ids, scal, rs, cs);
    temp_kernel<<<1, 1, 0, stream>>>(scal, (const int*)(scal + 5));
    gemm_kernel<1><<<1024, 256, 0, stream>>>(vhat, that_, ids, scal, rs, cs);
    final_kernel<<<1, 256, 0, stream>>>(scal, rs, cs, cntf, (float*)d_out);
}

// Round 2
// 141.431 us; speedup vs baseline: 1.2170x; 1.2170x over previous
//
#include <hip/hip_runtime.h>
#include <hip/hip_bf16.h>

#define NB 4096
#define DD 768
#define NT 24            // 768 / BK, BK = 32

typedef __bf16 bf16x8 __attribute__((ext_vector_type(8)));
typedef float f32x4 __attribute__((ext_vector_type(4)));
typedef unsigned int uint;

#define MEMFENCE asm volatile("" ::: "memory")

// ---------------- normalize: f32 row -> bf16 L2-normalized row ----------------
__global__ __launch_bounds__(256) void normalize_kernel(
    const float* __restrict__ vf, const float* __restrict__ tf,
    __hip_bfloat16* __restrict__ vhat, __hip_bfloat16* __restrict__ that_)
{
    int row = blockIdx.x;
    const float* src;
    __hip_bfloat16* dst;
    if (row < NB) { src = vf + (size_t)row * DD; dst = vhat + (size_t)row * DD; }
    else          { src = tf + (size_t)(row - NB) * DD; dst = that_ + (size_t)(row - NB) * DD; }
    int t = threadIdx.x;
    float x0 = src[t], x1 = src[t + 256], x2 = src[t + 512];
    float s = x0 * x0 + x1 * x1 + x2 * x2;
    #pragma unroll
    for (int off = 32; off > 0; off >>= 1) s += __shfl_down(s, off, 64);
    __shared__ float wsum[4];
    int wid = t >> 6, lane = t & 63;
    if (lane == 0) wsum[wid] = s;
    __syncthreads();
    float tot = wsum[0] + wsum[1] + wsum[2] + wsum[3];
    float scale = 1.0f / sqrtf(tot);
    dst[t]       = __float2bfloat16(x0 * scale);
    dst[t + 256] = __float2bfloat16(x1 * scale);
    dst[t + 512] = __float2bfloat16(x2 * scale);
}

// ---------------- cnt[i] = #{j : ids[j]==ids[i]} (includes self) ----------------
__global__ __launch_bounds__(256) void cnt_kernel(
    const int* __restrict__ ids, float* __restrict__ cntf, int* __restrict__ num_pos)
{
    __shared__ int sh[512];
    int i = blockIdx.x * 256 + threadIdx.x;
    int my = ids[i];
    int c = 0;
    for (int base = 0; base < NB; base += 512) {
        sh[threadIdx.x]       = ids[base + threadIdx.x];
        sh[threadIdx.x + 256] = ids[base + threadIdx.x + 256];
        __syncthreads();
        #pragma unroll 16
        for (int j = 0; j < 512; ++j) c += (sh[j] == my);
        __syncthreads();
    }
    cntf[i] = (float)c;
    atomicAdd(num_pos, c);
}

// ---------------- staging: linear LDS dest, pre-swizzled global source ----------------
// Logical element A[row][k] lives at LDS byte row*64 + ((k/8) ^ ((row>>1)&3))*16 + (k%8)*2.
// global_load_lds writes wave-uniform base + lane*16 (linear), so the lane loads the
// global chunk c_log = c_phys ^ ((srow>>1)&3) to land the swizzle (rule #21).
__device__ __forceinline__ void stage_tile(
    __hip_bfloat16* As, __hip_bfloat16* Bs,
    const __hip_bfloat16* aSrc, const __hip_bfloat16* bSrc,
    int k0, int wid, int lane)
{
    int srow = lane >> 2;                          // 0..15
    int clog = (lane & 3) ^ ((lane >> 3) & 3);     // pre-swizzled source chunk
    #pragma unroll
    for (int p = 0; p < 2; ++p) {
        int rb = p * 64 + wid * 16;
        const __hip_bfloat16* ga = aSrc + (size_t)(rb + srow) * DD + k0 + clog * 8;
        __builtin_amdgcn_global_load_lds(
            (const __attribute__((address_space(1))) void*)ga,
            (__attribute__((address_space(3))) void*)(As + rb * 32), 16, 0, 0);
        const __hip_bfloat16* gb = bSrc + (size_t)(rb + srow) * DD + k0 + clog * 8;
        __builtin_amdgcn_global_load_lds(
            (const __attribute__((address_space(1))) void*)gb,
            (__attribute__((address_space(3))) void*)(Bs + rb * 32), 16, 0, 0);
    }
}

// ---------------- GEMM: sim tile = vhat(128 rows) x that(128 rows)^T ----------------
// MODE 0: stats {total, S_mf, trace}; if STORE also write bf16 sim in fragment layout.
// MODE 1: (fallback) recompute sim, accumulate row/col exp sums.
template <int MODE, bool STORE>
__global__ __launch_bounds__(256) void gemm_kernel(
    const __hip_bfloat16* __restrict__ vhat, const __hip_bfloat16* __restrict__ that_,
    const int* __restrict__ ids, float* __restrict__ scal,
    float* __restrict__ rs, float* __restrict__ cs, uint4* __restrict__ simbuf)
{
    __shared__ __hip_bfloat16 AsB[2][128 * 32];
    __shared__ __hip_bfloat16 BsB[2][128 * 32];
    __shared__ int   idr[128], idc[128];
    __shared__ float red[12];
    __shared__ float rs_l[128], cs_l[128];

    // XCD-chunked swizzle: 8 regions of 8x16 tiles (bijective, nwg=1024)
    int bid = blockIdx.x;
    int xcd = bid & 7, sidx = bid >> 3;
    int by = (xcd >> 1) * 8 + (sidx >> 4);
    int bx = (xcd & 1) * 16 + (sidx & 15);
    int rowBase = by * 128, colBase = bx * 128;

    int t = threadIdx.x;
    int wid = t >> 6, lane = t & 63;
    int wr = wid >> 1, wc = wid & 1;
    int fr = lane & 15;            // fragment row/col index
    int ck = lane >> 4;            // logical k-chunk 0..3
    int sw = (fr >> 1) & 3;        // read-side swizzle selector
    int roff = ((ck ^ sw) * 8);    // bf16 offset of 16B chunk within row

    if (MODE == 1) {
        if (t < 128) { rs_l[t] = 0.0f; cs_l[t] = 0.0f; }
    }

    f32x4 acc[4][4];
    #pragma unroll
    for (int m = 0; m < 4; ++m)
        #pragma unroll
        for (int n = 0; n < 4; ++n) acc[m][n] = (f32x4){0.f, 0.f, 0.f, 0.f};

    const __hip_bfloat16* aSrc = vhat  + (size_t)rowBase * DD;
    const __hip_bfloat16* bSrc = that_ + (size_t)colBase * DD;

    // prologue
    stage_tile(AsB[0], BsB[0], aSrc, bSrc, 0, wid, lane);
    asm volatile("s_waitcnt vmcnt(0)" ::: "memory");
    __builtin_amdgcn_s_barrier();
    MEMFENCE;

    for (int it = 0; it < NT; ++it) {
        int cur = it & 1;
        if (it + 1 < NT)
            stage_tile(AsB[cur ^ 1], BsB[cur ^ 1], aSrc, bSrc, (it + 1) * 32, wid, lane);

        const __hip_bfloat16* Acur = AsB[cur];
        const __hip_bfloat16* Bcur = BsB[cur];
        bf16x8 a[4], b[4];
        #pragma unroll
        for (int m = 0; m < 4; ++m)
            a[m] = *(const bf16x8*)(Acur + (wr * 64 + m * 16 + fr) * 32 + roff);
        #pragma unroll
        for (int n = 0; n < 4; ++n)
            b[n] = *(const bf16x8*)(Bcur + (wc * 64 + n * 16 + fr) * 32 + roff);
        #pragma unroll
        for (int m = 0; m < 4; ++m)
            #pragma unroll
            for (int n = 0; n < 4; ++n)
                acc[m][n] = __builtin_amdgcn_mfma_f32_16x16x32_bf16(a[m], b[n], acc[m][n], 0, 0, 0);

        asm volatile("s_waitcnt vmcnt(0)" ::: "memory");  // next tile staged
        __builtin_amdgcn_s_barrier();                     // all waves done reading cur
        MEMFENCE;
    }

    int g = lane >> 4;  // C/D layout: col = lane&15, row = g*4 + reg   [m89-verified]

    if (MODE == 0) {
        __syncthreads();
        if (t < 128) { idr[t] = ids[rowBase + t]; idc[t] = ids[colBase + t]; }
        __syncthreads();
        float tsum = 0.f, msum = 0.f, dsum = 0.f;
        #pragma unroll
        for (int m = 0; m < 4; ++m) {
            int rl = wr * 64 + m * 16 + g * 4;
            #pragma unroll
            for (int n = 0; n < 4; ++n) {
                int cl = wc * 64 + n * 16 + fr;
                int colId = idc[cl];
                int gj = colBase + cl;
                #pragma unroll
                for (int r = 0; r < 4; ++r) {
                    float val = acc[m][n][r];
                    tsum += val;
                    if (idr[rl + r] == colId) msum += val;
                    if (rowBase + rl + r == gj) dsum += val;
                }
            }
        }
        #pragma unroll
        for (int off = 32; off > 0; off >>= 1) {
            tsum += __shfl_down(tsum, off, 64);
            msum += __shfl_down(msum, off, 64);
            dsum += __shfl_down(dsum, off, 64);
        }
        if (lane == 0) { red[wid] = tsum; red[4 + wid] = msum; red[8 + wid] = dsum; }
        __syncthreads();
        if (t == 0) {
            atomicAdd(&scal[0], red[0] + red[1] + red[2] + red[3]);
            atomicAdd(&scal[1], red[4] + red[5] + red[6] + red[7]);
            atomicAdd(&scal[2], red[8] + red[9] + red[10] + red[11]);
        }
        if (STORE) {
            int rec = by * 32 + bx;
            uint w32[32];
            #pragma unroll
            for (int m = 0; m < 4; ++m)
                #pragma unroll
                for (int n = 0; n < 4; ++n)
                    #pragma unroll
                    for (int rp = 0; rp < 2; ++rp) {
                        unsigned short u0 = __builtin_bit_cast(unsigned short,
                            __float2bfloat16(acc[m][n][rp * 2]));
                        unsigned short u1 = __builtin_bit_cast(unsigned short,
                            __float2bfloat16(acc[m][n][rp * 2 + 1]));
                        w32[m * 8 + n * 2 + rp] = (uint)u0 | ((uint)u1 << 16);
                    }
            uint4* dst = simbuf + (size_t)rec * 2048 + wid * 64 + lane;
            #pragma unroll
            for (int iv = 0; iv < 8; ++iv)
                dst[iv * 256] = make_uint4(w32[iv * 4], w32[iv * 4 + 1],
                                           w32[iv * 4 + 2], w32[iv * 4 + 3]);
        }
    } else {
        float invT = scal[4];
        #pragma unroll
        for (int m = 0; m < 4; ++m)
            #pragma unroll
            for (int n = 0; n < 4; ++n)
                #pragma unroll
                for (int r = 0; r < 4; ++r)
                    acc[m][n][r] = __expf((acc[m][n][r] - 1.0f) * invT);
        #pragma unroll
        for (int m = 0; m < 4; ++m) {
            #pragma unroll
            for (int r = 0; r < 4; ++r) {
                float rp = 0.f;
                #pragma unroll
                for (int n = 0; n < 4; ++n) rp += acc[m][n][r];
                rp += __shfl_xor(rp, 1, 64);
                rp += __shfl_xor(rp, 2, 64);
                rp += __shfl_xor(rp, 4, 64);
                rp += __shfl_xor(rp, 8, 64);
                if (fr == 0) atomicAdd(&rs_l[wr * 64 + m * 16 + g * 4 + r], rp);
            }
        }
        #pragma unroll
        for (int n = 0; n < 4; ++n) {
            float cp = 0.f;
            #pragma unroll
            for (int m = 0; m < 4; ++m)
                #pragma unroll
                for (int r = 0; r < 4; ++r) cp += acc[m][n][r];
            cp += __shfl_xor(cp, 16, 64);
            cp += __shfl_xor(cp, 32, 64);
            if (g == 0) atomicAdd(&cs_l[wc * 64 + n * 16 + fr], cp);
        }
        __syncthreads();
        if (t < 128)      atomicAdd(&rs[rowBase + t], rs_l[t]);
        else if (t < 256) atomicAdd(&cs[colBase + t - 128], cs_l[t - 128]);
    }
}

// ---------------- pass2: read stored bf16 sim fragments, exp, row/col sums ----------------
__global__ __launch_bounds__(256) void pass2_kernel(
    const uint4* __restrict__ simbuf, const float* __restrict__ scal,
    float* __restrict__ rs, float* __restrict__ cs)
{
    __shared__ float rs_l[128], cs_l[128];
    int p = blockIdx.x;
    int by = p >> 5, bx = p & 31;
    int t = threadIdx.x, wid = t >> 6, lane = t & 63;
    int wr = wid >> 1, wc = wid & 1;
    int fr = lane & 15, g = lane >> 4;
    if (t < 128) { rs_l[t] = 0.0f; cs_l[t] = 0.0f; }
    __syncthreads();
    float invT = scal[4];

    uint4 u[8];
    const uint4* base = simbuf + (size_t)p * 2048 + wid * 64 + lane;
    #pragma unroll
    for (int iv = 0; iv < 8; ++iv) u[iv] = base[iv * 256];
    uint w32[32];
    #pragma unroll
    for (int iv = 0; iv < 8; ++iv) {
        w32[iv * 4]     = u[iv].x; w32[iv * 4 + 1] = u[iv].y;
        w32[iv * 4 + 2] = u[iv].z; w32[iv * 4 + 3] = u[iv].w;
    }

    float cp[4] = {0.f, 0.f, 0.f, 0.f};
    #pragma unroll
    for (int m = 0; m < 4; ++m) {
        float rp[4] = {0.f, 0.f, 0.f, 0.f};
        #pragma unroll
        for (int n = 0; n < 4; ++n)
            #pragma unroll
            for (int q = 0; q < 2; ++q) {
                uint w = w32[m * 8 + n * 2 + q];
                float lo = __uint_as_float(w << 16);
                float hi = __uint_as_float(w & 0xffff0000u);
                float elo = __expf((lo - 1.0f) * invT);
                float ehi = __expf((hi - 1.0f) * invT);
                rp[q * 2]     += elo;
                rp[q * 2 + 1] += ehi;
                cp[n] += elo + ehi;
            }
        #pragma unroll
        for (int r = 0; r < 4; ++r) {
            float v = rp[r];
            v += __shfl_xor(v, 1, 64);
            v += __shfl_xor(v, 2, 64);
            v += __shfl_xor(v, 4, 64);
            v += __shfl_xor(v, 8, 64);
            if (fr == 0) atomicAdd(&rs_l[wr * 64 + m * 16 + g * 4 + r], v);
        }
    }
    #pragma unroll
    for (int n = 0; n < 4; ++n) {
        float v = cp[n];
        v += __shfl_xor(v, 16, 64);
        v += __shfl_xor(v, 32, 64);
        if (g == 0) atomicAdd(&cs_l[wc * 64 + n * 16 + fr], v);
    }
    __syncthreads();
    if (t < 128)      atomicAdd(&rs[by * 128 + t], rs_l[t]);
    else if (t < 256) atomicAdd(&cs[bx * 128 + t - 128], cs_l[t - 128]);
}

// ---------------- temp from global stats ----------------
__global__ void temp_kernel(float* scal, const int* num_pos_i)
{
    float total = scal[0], mf = scal[1], trace = scal[2];
    float np = (float)(*num_pos_i);
    float pos_cnt = np - (float)NB;
    float neg_cnt = (float)NB * (float)NB - np;
    float pos_mean = (mf - trace) / fmaxf(1.0f, pos_cnt);
    float neg_mean = (total - mf) / fmaxf(1.0f, neg_cnt);
    float sep = pos_mean - neg_mean;
    float temp = 0.07f * (0.8f + 0.4f * expf(-2.0f * sep));
    temp = fminf(fmaxf(temp, 0.04f), 0.2f);
    scal[3] = temp;
    scal[4] = 1.0f / temp;
}

// ---------------- final loss ----------------
__global__ __launch_bounds__(256) void final_kernel(
    const float* __restrict__ scal, const float* __restrict__ rs, const float* __restrict__ cs,
    const float* __restrict__ cntf, float* __restrict__ out)
{
    int t = threadIdx.x;
    float a = 0.0f, npl = 0.0f;
    for (int i = t; i < NB; i += 256) {
        float c = cntf[i];
        a += c * (logf(rs[i]) + logf(cs[i]));
        npl += c;
    }
    #pragma unroll
    for (int off = 32; off > 0; off >>= 1) {
        a += __shfl_down(a, off, 64);
        npl += __shfl_down(npl, off, 64);
    }
    __shared__ float ra[4], rn[4];
    int wid = t >> 6, lane = t & 63;
    if (lane == 0) { ra[wid] = a; rn[wid] = npl; }
    __syncthreads();
    if (t == 0) {
        float A  = ra[0] + ra[1] + ra[2] + ra[3];
        float np = rn[0] + rn[1] + rn[2] + rn[3];
        float invT = scal[4], mf = scal[1];
        float loss = (A + 2.0f * invT * (np - mf)) / (2.0f * np);
        out[0] = loss;
    }
}

extern "C" void kernel_launch(void* const* d_in, const int* in_sizes, int n_in,
                              void* d_out, int out_size, void* d_ws, size_t ws_size,
                              hipStream_t stream)
{
    const float* vf  = (const float*)d_in[0];
    const float* tf  = (const float*)d_in[1];
    const int*   ids = (const int*)d_in[2];

    float* ws_f = (float*)d_ws;
    float* scal = ws_f;                 // [0]=total [1]=S_mf [2]=trace [3]=temp [4]=1/temp [5]=num_pos(int)
    float* rs   = ws_f + 16;            // 4096
    float* cs   = ws_f + 16 + 4096;     // 4096
    float* cntf = ws_f + 16 + 8192;     // 4096 (fully overwritten)
    __hip_bfloat16* vhat  = (__hip_bfloat16*)((char*)d_ws + 65536);
    __hip_bfloat16* that_ = vhat + (size_t)NB * DD;

    const size_t SIM_OFF = 16777216;    // vhat/that end at ~12.65 MB
    uint4* simbuf = (uint4*)((char*)d_ws + SIM_OFF);
    bool store = ws_size >= SIM_OFF + (size_t)NB * NB * 2;

    // re-zero accumulators each call (graph replays accumulate via atomics)
    hipMemsetAsync(d_ws, 0, (16 + 8192) * sizeof(float), stream);

    normalize_kernel<<<2 * NB, 256, 0, stream>>>(vf, tf, vhat, that_);
    cnt_kernel<<<NB / 256, 256, 0, stream>>>(ids, cntf, (int*)(scal + 5));
    if (store) {
        gemm_kernel<0, true><<<1024, 256, 0, stream>>>(vhat, that_, ids, scal, rs, cs, simbuf);
        temp_kernel<<<1, 1, 0, stream>>>(scal, (const int*)(scal + 5));
        pass2_kernel<<<1024, 256, 0, stream>>>(simbuf, scal, rs, cs);
    } else {
        gemm_kernel<0, false><<<1024, 256, 0, stream>>>(vhat, that_, ids, scal, rs, cs, nullptr);
        temp_kernel<<<1, 1, 0, stream>>>(scal, (const int*)(scal + 5));
        gemm_kernel<1, false><<<1024, 256, 0, stream>>>(vhat, that_, ids, scal, rs, cs, nullptr);
    }
    final_kernel<<<1, 256, 0, stream>>>(scal, rs, cs, cntf, (float*)d_out);
}

// Round 3
// 120.101 us; speedup vs baseline: 1.4331x; 1.1776x over previous
//
#include <hip/hip_runtime.h>
#include <hip/hip_bf16.h>

#define NB 4096
#define DD 768
#define NKT 24            // K-tiles of BK=32: 768/32

typedef __bf16 bf16x8 __attribute__((ext_vector_type(8)));
typedef float f32x4 __attribute__((ext_vector_type(4)));
typedef unsigned int uint;

#define MEMFENCE asm volatile("" ::: "memory")
#define WAITVM(N) asm volatile("s_waitcnt vmcnt(" #N ")" ::: "memory")

// ---------------- normalize: f32 row -> bf16 L2-normalized row ----------------
__global__ __launch_bounds__(256) void normalize_kernel(
    const float* __restrict__ vf, const float* __restrict__ tf,
    __hip_bfloat16* __restrict__ vhat, __hip_bfloat16* __restrict__ that_)
{
    int row = blockIdx.x;
    const float* src;
    __hip_bfloat16* dst;
    if (row < NB) { src = vf + (size_t)row * DD; dst = vhat + (size_t)row * DD; }
    else          { src = tf + (size_t)(row - NB) * DD; dst = that_ + (size_t)(row - NB) * DD; }
    int t = threadIdx.x;
    float x0 = src[t], x1 = src[t + 256], x2 = src[t + 512];
    float s = x0 * x0 + x1 * x1 + x2 * x2;
    #pragma unroll
    for (int off = 32; off > 0; off >>= 1) s += __shfl_down(s, off, 64);
    __shared__ float wsum[4];
    int wid = t >> 6, lane = t & 63;
    if (lane == 0) wsum[wid] = s;
    __syncthreads();
    float tot = wsum[0] + wsum[1] + wsum[2] + wsum[3];
    float scale = 1.0f / sqrtf(tot);
    dst[t]       = __float2bfloat16(x0 * scale);
    dst[t + 256] = __float2bfloat16(x1 * scale);
    dst[t + 512] = __float2bfloat16(x2 * scale);
}

// ---------------- cnt[i] = #{j : ids[j]==ids[i]} (includes self) ----------------
__global__ __launch_bounds__(256) void cnt_kernel(
    const int* __restrict__ ids, float* __restrict__ cntf, int* __restrict__ num_pos)
{
    __shared__ int sh[512];
    int i = blockIdx.x * 256 + threadIdx.x;
    int my = ids[i];
    int c = 0;
    for (int base = 0; base < NB; base += 512) {
        sh[threadIdx.x]       = ids[base + threadIdx.x];
        sh[threadIdx.x + 256] = ids[base + threadIdx.x + 256];
        __syncthreads();
        #pragma unroll 16
        for (int j = 0; j < 512; ++j) c += (sh[j] == my);
        __syncthreads();
    }
    cntf[i] = (float)c;
    atomicAdd(num_pos, c);
}

// ---------------- staging: one K-tile unit = A[256][32] + B[256][32] (32 KB) ----------------
// Swizzle (both-sides, rule #21): logical chunk c (16B) of row r sits at phys chunk c^(r&3).
// global_load_lds dest is linear (base+lane*16); lane's source chunk = (lane&3)^((lane>>2)&3).
// Waves 0-3 stage A rows w*64.., waves 4-7 stage B rows (w-4)*64..; inst i covers 16 rows.
__device__ __forceinline__ void stage_range(
    __hip_bfloat16* ldsAll,
    const __hip_bfloat16* __restrict__ vhat, const __hip_bfloat16* __restrict__ that_,
    int rowBase, int colBase, int T, int i0, int i1, int wid, int lane)
{
    int u = T & 3;
    int k0 = T * 32;
    const __hip_bfloat16* src = (wid >= 4) ? that_ : vhat;
    int tb = (wid >= 4) ? colBase : rowBase;
    int w4 = wid & 3;
    int logc = (lane & 3) ^ ((lane >> 2) & 3);
    int rowIn = w4 * 64 + (lane >> 2);
    __hip_bfloat16* dbase = ldsAll + u * 16384 + ((wid >= 4) ? 8192 : 0) + w4 * 2048;
    #pragma unroll
    for (int i = i0; i <= i1; ++i) {
        const __hip_bfloat16* g = src + (size_t)(tb + rowIn + i * 16) * DD + k0 + logc * 8;
        __builtin_amdgcn_global_load_lds(
            (const __attribute__((address_space(1))) void*)g,
            (__attribute__((address_space(3))) void*)(dbase + i * 512),
            16, 0, 0);
    }
}

// ---------------- GEMM: 256x256 tile, 8 waves (2M x 4N), BK=32, 4-deep ring ----------------
// MODE 0: stats {total, S_mf, trace}; if STORE also write bf16 sim fragments.
// MODE 1: (fallback) exp((s-1)/T) row/col sums.
template <int MODE, bool STORE>
__global__ __launch_bounds__(512, 2) void gemm_kernel(
    const __hip_bfloat16* __restrict__ vhat, const __hip_bfloat16* __restrict__ that_,
    const int* __restrict__ ids, float* __restrict__ scal,
    float* __restrict__ rs, float* __restrict__ cs, uint4* __restrict__ simbuf)
{
    __shared__ __hip_bfloat16 ldsAll[4 * 16384];   // 128 KB: 4 ring units
    __shared__ int idr[256], idc[256];
    __shared__ float red[24];
    __shared__ float rs_l[256], cs_l[256];

    // XCD-chunked bijective swizzle: 8 regions of 4by x 8bx (grid 256 = 16x16)
    int bid = blockIdx.x;
    int rg = bid & 7, sq = bid >> 3;
    int by = (rg >> 1) * 4 + (sq >> 3);
    int bx = (rg & 1) * 8 + (sq & 7);
    int rowBase = by * 256, colBase = bx * 256;

    int t = threadIdx.x;
    int wid = t >> 6, lane = t & 63;
    int wr = wid >> 2, wc = wid & 3;         // wave = 128-row x 64-col output block
    int fr = lane & 15, g = lane >> 4;

    if (MODE == 1) {
        if (t < 256) { rs_l[t] = 0.0f; cs_l[t] = 0.0f; }
    }

    f32x4 acc[8][4];
    #pragma unroll
    for (int m = 0; m < 8; ++m)
        #pragma unroll
        for (int n = 0; n < 4; ++n) acc[m][n] = (f32x4){0.f, 0.f, 0.f, 0.f};

    // LDS read offsets (bf16 elems). phys chunk = g ^ (fr&3); rows stride 32 elems.
    int pcoff = ((g ^ (fr & 3)) * 8);
    int aoff = (wr * 128 + fr) * 32 + pcoff;
    int boff = 8192 + (wc * 64 + fr) * 32 + pcoff;

    // prologue: stage tiles 0,1,2 (12 loads/thread); need tile0 done -> vmcnt(8)
    stage_range(ldsAll, vhat, that_, rowBase, colBase, 0, 0, 3, wid, lane);
    stage_range(ldsAll, vhat, that_, rowBase, colBase, 1, 0, 3, wid, lane);
    stage_range(ldsAll, vhat, that_, rowBase, colBase, 2, 0, 3, wid, lane);
    WAITVM(8);
    __builtin_amdgcn_s_barrier();
    MEMFENCE;

    for (int T = 0; T < NKT; ++T) {
        const __hip_bfloat16* U = ldsAll + (T & 3) * 16384;
        // ---- phase A: stage half of T+3, compute m=0..3 ----
        if (T + 3 < NKT)
            stage_range(ldsAll, vhat, that_, rowBase, colBase, T + 3, 0, 1, wid, lane);
        bf16x8 a0[4], bb[4];
        #pragma unroll
        for (int m = 0; m < 4; ++m) a0[m] = *(const bf16x8*)(U + aoff + m * 512);
        #pragma unroll
        for (int n = 0; n < 4; ++n) bb[n] = *(const bf16x8*)(U + boff + n * 512);
        __builtin_amdgcn_s_setprio(1);
        #pragma unroll
        for (int m = 0; m < 4; ++m)
            #pragma unroll
            for (int n = 0; n < 4; ++n)
                acc[m][n] = __builtin_amdgcn_mfma_f32_16x16x32_bf16(a0[m], bb[n], acc[m][n], 0, 0, 0);
        __builtin_amdgcn_s_setprio(0);
        // ---- phase B: stage other half of T+3, compute m=4..7 ----
        if (T + 3 < NKT)
            stage_range(ldsAll, vhat, that_, rowBase, colBase, T + 3, 2, 3, wid, lane);
        bf16x8 a1[4];
        #pragma unroll
        for (int m = 0; m < 4; ++m) a1[m] = *(const bf16x8*)(U + aoff + (m + 4) * 512);
        __builtin_amdgcn_s_setprio(1);
        #pragma unroll
        for (int m = 0; m < 4; ++m)
            #pragma unroll
            for (int n = 0; n < 4; ++n)
                acc[m + 4][n] = __builtin_amdgcn_mfma_f32_16x16x32_bf16(a1[m], bb[n], acc[m + 4][n], 0, 0, 0);
        __builtin_amdgcn_s_setprio(0);
        // ---- boundary: tile T+1 must be staged; leave T+2/T+3 loads in flight ----
        if (T < NKT - 3)       { WAITVM(8); }
        else if (T == NKT - 3) { WAITVM(4); }
        else if (T == NKT - 2) { WAITVM(0); }
        __builtin_amdgcn_s_barrier();
        MEMFENCE;
    }

    // C/D layout per frag: col = fr, row = g*4 + reg   [m89-verified]
    if (MODE == 0) {
        if (t < 256) idr[t] = ids[rowBase + t];
        else         idc[t - 256] = ids[colBase + (t - 256)];
        __syncthreads();
        float tsum = 0.f, msum = 0.f, dsum = 0.f;
        #pragma unroll
        for (int m = 0; m < 8; ++m) {
            int rl = wr * 128 + m * 16 + g * 4;
            #pragma unroll
            for (int n = 0; n < 4; ++n) {
                int cl = wc * 64 + n * 16 + fr;
                int colId = idc[cl];
                int gj = colBase + cl;
                #pragma unroll
                for (int r = 0; r < 4; ++r) {
                    float val = acc[m][n][r];
                    tsum += val;
                    if (idr[rl + r] == colId) msum += val;
                    if (rowBase + rl + r == gj) dsum += val;
                }
            }
        }
        #pragma unroll
        for (int off = 32; off > 0; off >>= 1) {
            tsum += __shfl_down(tsum, off, 64);
            msum += __shfl_down(msum, off, 64);
            dsum += __shfl_down(dsum, off, 64);
        }
        if (lane == 0) { red[wid] = tsum; red[8 + wid] = msum; red[16 + wid] = dsum; }
        __syncthreads();
        if (t == 0) {
            float s0 = 0.f, s1 = 0.f, s2 = 0.f;
            #pragma unroll
            for (int w = 0; w < 8; ++w) { s0 += red[w]; s1 += red[8 + w]; s2 += red[16 + w]; }
            atomicAdd(&scal[0], s0);
            atomicAdd(&scal[1], s1);
            atomicAdd(&scal[2], s2);
        }
        if (STORE) {
            int rec = by * 16 + bx;           // logical tile id (swizzle-independent)
            uint w32[64];
            #pragma unroll
            for (int m = 0; m < 8; ++m)
                #pragma unroll
                for (int n = 0; n < 4; ++n)
                    #pragma unroll
                    for (int qq = 0; qq < 2; ++qq) {
                        unsigned short u0 = __builtin_bit_cast(unsigned short,
                            __float2bfloat16(acc[m][n][qq * 2]));
                        unsigned short u1 = __builtin_bit_cast(unsigned short,
                            __float2bfloat16(acc[m][n][qq * 2 + 1]));
                        w32[2 * (m * 4 + n) + qq] = (uint)u0 | ((uint)u1 << 16);
                    }
            uint4* dst = simbuf + ((size_t)(rec * 8 + wid) * 16) * 64 + lane;
            #pragma unroll
            for (int iv = 0; iv < 16; ++iv)
                dst[iv * 64] = make_uint4(w32[iv * 4], w32[iv * 4 + 1],
                                          w32[iv * 4 + 2], w32[iv * 4 + 3]);
        }
    } else {
        float invT = scal[4];
        #pragma unroll
        for (int m = 0; m < 8; ++m)
            #pragma unroll
            for (int n = 0; n < 4; ++n)
                #pragma unroll
                for (int r = 0; r < 4; ++r)
                    acc[m][n][r] = __expf((acc[m][n][r] - 1.0f) * invT);
        #pragma unroll
        for (int m = 0; m < 8; ++m) {
            #pragma unroll
            for (int r = 0; r < 4; ++r) {
                float rp = 0.f;
                #pragma unroll
                for (int n = 0; n < 4; ++n) rp += acc[m][n][r];
                rp += __shfl_xor(rp, 1, 64);
                rp += __shfl_xor(rp, 2, 64);
                rp += __shfl_xor(rp, 4, 64);
                rp += __shfl_xor(rp, 8, 64);
                if (fr == 0) atomicAdd(&rs_l[wr * 128 + m * 16 + g * 4 + r], rp);
            }
        }
        #pragma unroll
        for (int n = 0; n < 4; ++n) {
            float cp = 0.f;
            #pragma unroll
            for (int m = 0; m < 8; ++m)
                #pragma unroll
                for (int r = 0; r < 4; ++r) cp += acc[m][n][r];
            cp += __shfl_xor(cp, 16, 64);
            cp += __shfl_xor(cp, 32, 64);
            if (g == 0) atomicAdd(&cs_l[wc * 64 + n * 16 + fr], cp);
        }
        __syncthreads();
        if (t < 256) {
            atomicAdd(&rs[rowBase + t], rs_l[t]);
            atomicAdd(&cs[colBase + t], cs_l[t]);
        }
    }
}

// ---------------- pass2: read stored bf16 sim fragments, exp, row/col sums ----------------
__global__ __launch_bounds__(256) void pass2_kernel(
    const uint4* __restrict__ simbuf, const float* __restrict__ scal,
    float* __restrict__ rs, float* __restrict__ cs)
{
    __shared__ float rs_l[128], cs_l[256];
    int q = blockIdx.x, rec = q >> 1, h = q & 1;
    int by = rec >> 4, bx = rec & 15;
    int rowBase = by * 256 + h * 128, colBase = bx * 256;
    int t = threadIdx.x, w4 = t >> 6, lane = t & 63;
    int gw = h * 4 + w4;                 // gemm wave id; wr = h, wc = w4
    int wc = gw & 3;
    int fr = lane & 15, g = lane >> 4;
    if (t < 128) rs_l[t] = 0.f;
    cs_l[t] = 0.f;
    __syncthreads();
    float invT = scal[4];

    const uint4* base = simbuf + ((size_t)(rec * 8 + gw) * 16) * 64 + lane;
    uint4 u16[16];
    #pragma unroll
    for (int iv = 0; iv < 16; ++iv) u16[iv] = base[iv * 64];
    uint w32[64];
    #pragma unroll
    for (int iv = 0; iv < 16; ++iv) {
        w32[iv * 4]     = u16[iv].x; w32[iv * 4 + 1] = u16[iv].y;
        w32[iv * 4 + 2] = u16[iv].z; w32[iv * 4 + 3] = u16[iv].w;
    }

    float cp[4] = {0.f, 0.f, 0.f, 0.f};
    #pragma unroll
    for (int m = 0; m < 8; ++m) {
        float rp[4] = {0.f, 0.f, 0.f, 0.f};
        #pragma unroll
        for (int n = 0; n < 4; ++n)
            #pragma unroll
            for (int qq = 0; qq < 2; ++qq) {
                uint w = w32[2 * (m * 4 + n) + qq];
                float lo = __uint_as_float(w << 16);
                float hi = __uint_as_float(w & 0xffff0000u);
                float elo = __expf((lo - 1.0f) * invT);
                float ehi = __expf((hi - 1.0f) * invT);
                rp[qq * 2]     += elo;
                rp[qq * 2 + 1] += ehi;
                cp[n] += elo + ehi;
            }
        #pragma unroll
        for (int r = 0; r < 4; ++r) {
            float v = rp[r];
            v += __shfl_xor(v, 1, 64);
            v += __shfl_xor(v, 2, 64);
            v += __shfl_xor(v, 4, 64);
            v += __shfl_xor(v, 8, 64);
            if (fr == 0) atomicAdd(&rs_l[m * 16 + g * 4 + r], v);
        }
    }
    #pragma unroll
    for (int n = 0; n < 4; ++n) {
        float v = cp[n];
        v += __shfl_xor(v, 16, 64);
        v += __shfl_xor(v, 32, 64);
        if (g == 0) atomicAdd(&cs_l[wc * 64 + n * 16 + fr], v);
    }
    __syncthreads();
    if (t < 128) atomicAdd(&rs[rowBase + t], rs_l[t]);
    atomicAdd(&cs[colBase + t], cs_l[t]);
}

// ---------------- temp from global stats ----------------
__global__ void temp_kernel(float* scal, const int* num_pos_i)
{
    float total = scal[0], mf = scal[1], trace = scal[2];
    float np = (float)(*num_pos_i);
    float pos_cnt = np - (float)NB;
    float neg_cnt = (float)NB * (float)NB - np;
    float pos_mean = (mf - trace) / fmaxf(1.0f, pos_cnt);
    float neg_mean = (total - mf) / fmaxf(1.0f, neg_cnt);
    float sep = pos_mean - neg_mean;
    float temp = 0.07f * (0.8f + 0.4f * expf(-2.0f * sep));
    temp = fminf(fmaxf(temp, 0.04f), 0.2f);
    scal[3] = temp;
    scal[4] = 1.0f / temp;
}

// ---------------- final loss ----------------
__global__ __launch_bounds__(256) void final_kernel(
    const float* __restrict__ scal, const float* __restrict__ rs, const float* __restrict__ cs,
    const float* __restrict__ cntf, float* __restrict__ out)
{
    int t = threadIdx.x;
    float a = 0.0f, npl = 0.0f;
    for (int i = t; i < NB; i += 256) {
        float c = cntf[i];
        a += c * (logf(rs[i]) + logf(cs[i]));
        npl += c;
    }
    #pragma unroll
    for (int off = 32; off > 0; off >>= 1) {
        a += __shfl_down(a, off, 64);
        npl += __shfl_down(npl, off, 64);
    }
    __shared__ float ra[4], rn[4];
    int wid = t >> 6, lane = t & 63;
    if (lane == 0) { ra[wid] = a; rn[wid] = npl; }
    __syncthreads();
    if (t == 0) {
        float A  = ra[0] + ra[1] + ra[2] + ra[3];
        float np = rn[0] + rn[1] + rn[2] + rn[3];
        float invT = scal[4], mf = scal[1];
        // lse_row[i] = 1/temp + log(rs[i]); v2t+t2v = sum cnt*(lse_r+lse_c) - 2*mf/temp
        float loss = (A + 2.0f * invT * (np - mf)) / (2.0f * np);
        out[0] = loss;
    }
}

extern "C" void kernel_launch(void* const* d_in, const int* in_sizes, int n_in,
                              void* d_out, int out_size, void* d_ws, size_t ws_size,
                              hipStream_t stream)
{
    const float* vf  = (const float*)d_in[0];
    const float* tf  = (const float*)d_in[1];
    const int*   ids = (const int*)d_in[2];

    float* ws_f = (float*)d_ws;
    float* scal = ws_f;                 // [0]=total [1]=S_mf [2]=trace [3]=temp [4]=1/temp [5]=num_pos(int)
    float* rs   = ws_f + 16;            // 4096
    float* cs   = ws_f + 16 + 4096;     // 4096
    float* cntf = ws_f + 16 + 8192;     // 4096 (fully overwritten)
    __hip_bfloat16* vhat  = (__hip_bfloat16*)((char*)d_ws + 65536);
    __hip_bfloat16* that_ = vhat + (size_t)NB * DD;

    const size_t SIM_OFF = 16777216;    // vhat/that end at ~12.65 MB
    uint4* simbuf = (uint4*)((char*)d_ws + SIM_OFF);
    bool store = ws_size >= SIM_OFF + (size_t)NB * NB * 2;

    // re-zero accumulators each call (graph replays accumulate via atomics)
    hipMemsetAsync(d_ws, 0, (16 + 8192) * sizeof(float), stream);

    normalize_kernel<<<2 * NB, 256, 0, stream>>>(vf, tf, vhat, that_);
    cnt_kernel<<<NB / 256, 256, 0, stream>>>(ids, cntf, (int*)(scal + 5));
    if (store) {
        gemm_kernel<0, true><<<256, 512, 0, stream>>>(vhat, that_, ids, scal, rs, cs, simbuf);
        temp_kernel<<<1, 1, 0, stream>>>(scal, (const int*)(scal + 5));
        pass2_kernel<<<512, 256, 0, stream>>>(simbuf, scal, rs, cs);
    } else {
        gemm_kernel<0, false><<<256, 512, 0, stream>>>(vhat, that_, ids, scal, rs, cs, nullptr);
        temp_kernel<<<1, 1, 0, stream>>>(scal, (const int*)(scal + 5));
        gemm_kernel<1, false><<<256, 512, 0, stream>>>(vhat, that_, ids, scal, rs, cs, nullptr);
    }
    final_kernel<<<1, 256, 0, stream>>>(scal, rs, cs, cntf, (float*)d_out);
}

// Round 4
// 111.257 us; speedup vs baseline: 1.5470x; 1.0795x over previous
//
#include <hip/hip_runtime.h>
#include <hip/hip_bf16.h>

#define NB 4096
#define DD 768
#define NKT 24            // K-tiles of BK=32: 768/32

typedef __bf16 bf16x8 __attribute__((ext_vector_type(8)));
typedef float f32x4 __attribute__((ext_vector_type(4)));
typedef unsigned int uint;

#define WAITVM(N) asm volatile("s_waitcnt vmcnt(" #N ")" ::: "memory")
#define WAITLGKM0 asm volatile("s_waitcnt lgkmcnt(0)" ::: "memory")

// ---------------- temp from global stats (shared device helper) ----------------
__device__ __forceinline__ float compute_invT(const float* scal, const int* num_pos_i)
{
    float total = scal[0], mf = scal[1], trace = scal[2];
    float np = (float)(*num_pos_i);
    float pos_cnt = np - (float)NB;
    float neg_cnt = (float)NB * (float)NB - np;
    float pos_mean = (mf - trace) / fmaxf(1.0f, pos_cnt);
    float neg_mean = (total - mf) / fmaxf(1.0f, neg_cnt);
    float sep = pos_mean - neg_mean;
    float temp = 0.07f * (0.8f + 0.4f * expf(-2.0f * sep));
    temp = fminf(fmaxf(temp, 0.04f), 0.2f);
    return 1.0f / temp;
}

// ---------------- prep: normalize rows (blocks 0..8191) + cnt (blocks 8192..8207) ----------------
__global__ __launch_bounds__(256) void prep_kernel(
    const float* __restrict__ vf, const float* __restrict__ tf, const int* __restrict__ ids,
    __hip_bfloat16* __restrict__ vhat, __hip_bfloat16* __restrict__ that_,
    float* __restrict__ cntf, int* __restrict__ num_pos)
{
    int b = blockIdx.x;
    int t = threadIdx.x;
    if (b < 2 * NB) {
        const float* src;
        __hip_bfloat16* dst;
        if (b < NB) { src = vf + (size_t)b * DD; dst = vhat + (size_t)b * DD; }
        else        { src = tf + (size_t)(b - NB) * DD; dst = that_ + (size_t)(b - NB) * DD; }
        float x0 = src[t], x1 = src[t + 256], x2 = src[t + 512];
        float s = x0 * x0 + x1 * x1 + x2 * x2;
        #pragma unroll
        for (int off = 32; off > 0; off >>= 1) s += __shfl_down(s, off, 64);
        __shared__ float wsum[4];
        int wid = t >> 6, lane = t & 63;
        if (lane == 0) wsum[wid] = s;
        __syncthreads();
        float tot = wsum[0] + wsum[1] + wsum[2] + wsum[3];
        float scale = 1.0f / sqrtf(tot);
        dst[t]       = __float2bfloat16(x0 * scale);
        dst[t + 256] = __float2bfloat16(x1 * scale);
        dst[t + 512] = __float2bfloat16(x2 * scale);
    } else {
        __shared__ int sh[512];
        int i = (b - 2 * NB) * 256 + t;
        int my = ids[i];
        int c = 0;
        for (int base = 0; base < NB; base += 512) {
            sh[t]       = ids[base + t];
            sh[t + 256] = ids[base + t + 256];
            __syncthreads();
            #pragma unroll 16
            for (int j = 0; j < 512; ++j) c += (sh[j] == my);
            __syncthreads();
        }
        cntf[i] = (float)c;
        atomicAdd(num_pos, c);
    }
}

// ---------------- staging: one K-tile unit = A[256][32] + B[256][32] (32 KB) ----------------
// Swizzle (both sides, rule #21): logical chunk c (16B) of row r at phys chunk c ^ ((r>>1)&3).
// global_load_lds dest is linear (base+lane*16); lane's global source chunk = (lane&3)^((lane>>3)&3).
// R2 measured this exact scheme at 0 bank conflicts (2-way max aliasing = free, m136).
__device__ __forceinline__ void stage_range(
    __hip_bfloat16* ldsAll,
    const __hip_bfloat16* __restrict__ vhat, const __hip_bfloat16* __restrict__ that_,
    int rowBase, int colBase, int T, int i0, int i1, int wid, int lane)
{
    int u = T & 3;
    int k0 = T * 32;
    const __hip_bfloat16* src = (wid >= 4) ? that_ : vhat;
    int tb = (wid >= 4) ? colBase : rowBase;
    int w4 = wid & 3;
    int logc = (lane & 3) ^ ((lane >> 3) & 3);
    int rowIn = w4 * 64 + (lane >> 2);
    __hip_bfloat16* dbase = ldsAll + u * 16384 + ((wid >= 4) ? 8192 : 0) + w4 * 2048;
    #pragma unroll
    for (int i = i0; i <= i1; ++i) {
        const __hip_bfloat16* g = src + (size_t)(tb + rowIn + i * 16) * DD + k0 + logc * 8;
        __builtin_amdgcn_global_load_lds(
            (const __attribute__((address_space(1))) void*)g,
            (__attribute__((address_space(3))) void*)(dbase + i * 512),
            16, 0, 0);
    }
}

// ---------------- GEMM: 256x256 tile, 8 waves (2M x 4N), BK=32, 4-deep ring ----------------
// m201-style phase schedule: {ds_read cluster || stage issue -> BAR -> lgkmcnt(0) -> MFMA16 -> BAR},
// counted vmcnt only at tile boundaries (T4), setprio around MFMA (T5).
// MODE 0: stats {total, S_mf, trace}; if STORE also write bf16 sim fragments.
// MODE 1: (fallback) exp((s-1)/T) row/col sums.
template <int MODE, bool STORE>
__global__ __launch_bounds__(512, 2) void gemm_kernel(
    const __hip_bfloat16* __restrict__ vhat, const __hip_bfloat16* __restrict__ that_,
    const int* __restrict__ ids, float* __restrict__ scal,
    float* __restrict__ rs, float* __restrict__ cs, uint4* __restrict__ simbuf)
{
    __shared__ __hip_bfloat16 ldsAll[4 * 16384];   // 128 KB: 4 ring units
    __shared__ int idr[256], idc[256];
    __shared__ float red[24];
    __shared__ float rs_l[256], cs_l[256];

    // XCD-chunked bijective swizzle: 8 regions of 4by x 8bx (grid 256 = 16x16)
    int bid = blockIdx.x;
    int rg = bid & 7, sq = bid >> 3;
    int by = (rg >> 1) * 4 + (sq >> 3);
    int bx = (rg & 1) * 8 + (sq & 7);
    int rowBase = by * 256, colBase = bx * 256;

    int t = threadIdx.x;
    int wid = t >> 6, lane = t & 63;
    int wr = wid >> 2, wc = wid & 3;         // wave = 128-row x 64-col output block
    int fr = lane & 15, g = lane >> 4;

    if (MODE == 1) {
        if (t < 256) { rs_l[t] = 0.0f; cs_l[t] = 0.0f; }
    }

    f32x4 acc[8][4];
    #pragma unroll
    for (int m = 0; m < 8; ++m)
        #pragma unroll
        for (int n = 0; n < 4; ++n) acc[m][n] = (f32x4){0.f, 0.f, 0.f, 0.f};

    // LDS read offsets (bf16 elems): phys chunk = g ^ ((row>>1)&3); row bits 1-2 come from fr.
    int pcoff = ((g ^ ((fr >> 1) & 3)) * 8);
    int aoff = (wr * 128 + fr) * 32 + pcoff;
    int boff = 8192 + (wc * 64 + fr) * 32 + pcoff;

    // prologue: stage tiles 0,1,2 (12 loads/thread); tile0 complete -> vmcnt(8)
    stage_range(ldsAll, vhat, that_, rowBase, colBase, 0, 0, 3, wid, lane);
    stage_range(ldsAll, vhat, that_, rowBase, colBase, 1, 0, 3, wid, lane);
    stage_range(ldsAll, vhat, that_, rowBase, colBase, 2, 0, 3, wid, lane);
    WAITVM(8);
    __builtin_amdgcn_s_barrier();

    for (int T = 0; T < NKT; ++T) {
        const __hip_bfloat16* U = ldsAll + (T & 3) * 16384;
        // ======== phase A: reads(a0,bb) || stage half1(T+3) -> BAR -> MFMA m0..3 ========
        bf16x8 a0[4], bb[4];
        #pragma unroll
        for (int m = 0; m < 4; ++m) a0[m] = *(const bf16x8*)(U + aoff + m * 512);
        #pragma unroll
        for (int n = 0; n < 4; ++n) bb[n] = *(const bf16x8*)(U + boff + n * 512);
        if (T + 3 < NKT)
            stage_range(ldsAll, vhat, that_, rowBase, colBase, T + 3, 0, 1, wid, lane);
        __builtin_amdgcn_sched_barrier(0);
        __builtin_amdgcn_s_barrier();
        WAITLGKM0;
        __builtin_amdgcn_sched_barrier(0);
        __builtin_amdgcn_s_setprio(1);
        #pragma unroll
        for (int m = 0; m < 4; ++m)
            #pragma unroll
            for (int n = 0; n < 4; ++n)
                acc[m][n] = __builtin_amdgcn_mfma_f32_16x16x32_bf16(a0[m], bb[n], acc[m][n], 0, 0, 0);
        __builtin_amdgcn_s_setprio(0);
        __builtin_amdgcn_sched_barrier(0);
        __builtin_amdgcn_s_barrier();
        // ======== phase B: reads(a1) || stage half2(T+3) -> BAR -> MFMA m4..7 ========
        bf16x8 a1[4];
        #pragma unroll
        for (int m = 0; m < 4; ++m) a1[m] = *(const bf16x8*)(U + aoff + (m + 4) * 512);
        if (T + 3 < NKT)
            stage_range(ldsAll, vhat, that_, rowBase, colBase, T + 3, 2, 3, wid, lane);
        __builtin_amdgcn_sched_barrier(0);
        __builtin_amdgcn_s_barrier();
        WAITLGKM0;
        __builtin_amdgcn_sched_barrier(0);
        __builtin_amdgcn_s_setprio(1);
        #pragma unroll
        for (int m = 0; m < 4; ++m)
            #pragma unroll
            for (int n = 0; n < 4; ++n)
                acc[m + 4][n] = __builtin_amdgcn_mfma_f32_16x16x32_bf16(a1[m], bb[n], acc[m + 4][n], 0, 0, 0);
        __builtin_amdgcn_s_setprio(0);
        __builtin_amdgcn_sched_barrier(0);
        // ---- tile boundary: T+1 staged; keep T+2/T+3 loads in flight (never vmcnt 0 mid-loop) ----
        if (T < NKT - 3)       { WAITVM(8); }
        else if (T == NKT - 3) { WAITVM(4); }
        else if (T == NKT - 2) { WAITVM(0); }
        __builtin_amdgcn_s_barrier();
    }

    // C/D layout per frag: col = fr, row = g*4 + reg   [m89-verified]
    if (MODE == 0) {
        if (t < 256) idr[t] = ids[rowBase + t];
        else         idc[t - 256] = ids[colBase + (t - 256)];
        __syncthreads();
        float tsum = 0.f, msum = 0.f, dsum = 0.f;
        #pragma unroll
        for (int m = 0; m < 8; ++m) {
            int rl = wr * 128 + m * 16 + g * 4;
            #pragma unroll
            for (int n = 0; n < 4; ++n) {
                int cl = wc * 64 + n * 16 + fr;
                int colId = idc[cl];
                int gj = colBase + cl;
                #pragma unroll
                for (int r = 0; r < 4; ++r) {
                    float val = acc[m][n][r];
                    tsum += val;
                    if (idr[rl + r] == colId) msum += val;
                    if (rowBase + rl + r == gj) dsum += val;
                }
            }
        }
        #pragma unroll
        for (int off = 32; off > 0; off >>= 1) {
            tsum += __shfl_down(tsum, off, 64);
            msum += __shfl_down(msum, off, 64);
            dsum += __shfl_down(dsum, off, 64);
        }
        if (lane == 0) { red[wid] = tsum; red[8 + wid] = msum; red[16 + wid] = dsum; }
        __syncthreads();
        if (t == 0) {
            float s0 = 0.f, s1 = 0.f, s2 = 0.f;
            #pragma unroll
            for (int w = 0; w < 8; ++w) { s0 += red[w]; s1 += red[8 + w]; s2 += red[16 + w]; }
            atomicAdd(&scal[0], s0);
            atomicAdd(&scal[1], s1);
            atomicAdd(&scal[2], s2);
        }
        if (STORE) {
            int rec = by * 16 + bx;           // logical tile id (swizzle-independent)
            uint w32[64];
            #pragma unroll
            for (int m = 0; m < 8; ++m)
                #pragma unroll
                for (int n = 0; n < 4; ++n)
                    #pragma unroll
                    for (int qq = 0; qq < 2; ++qq) {
                        unsigned short u0 = __builtin_bit_cast(unsigned short,
                            __float2bfloat16(acc[m][n][qq * 2]));
                        unsigned short u1 = __builtin_bit_cast(unsigned short,
                            __float2bfloat16(acc[m][n][qq * 2 + 1]));
                        w32[2 * (m * 4 + n) + qq] = (uint)u0 | ((uint)u1 << 16);
                    }
            uint4* dst = simbuf + ((size_t)(rec * 8 + wid) * 16) * 64 + lane;
            #pragma unroll
            for (int iv = 0; iv < 16; ++iv)
                dst[iv * 64] = make_uint4(w32[iv * 4], w32[iv * 4 + 1],
                                          w32[iv * 4 + 2], w32[iv * 4 + 3]);
        }
    } else {
        float invT = scal[4];
        #pragma unroll
        for (int m = 0; m < 8; ++m)
            #pragma unroll
            for (int n = 0; n < 4; ++n)
                #pragma unroll
                for (int r = 0; r < 4; ++r)
                    acc[m][n][r] = __expf((acc[m][n][r] - 1.0f) * invT);
        #pragma unroll
        for (int m = 0; m < 8; ++m) {
            #pragma unroll
            for (int r = 0; r < 4; ++r) {
                float rp = 0.f;
                #pragma unroll
                for (int n = 0; n < 4; ++n) rp += acc[m][n][r];
                rp += __shfl_xor(rp, 1, 64);
                rp += __shfl_xor(rp, 2, 64);
                rp += __shfl_xor(rp, 4, 64);
                rp += __shfl_xor(rp, 8, 64);
                if (fr == 0) atomicAdd(&rs_l[wr * 128 + m * 16 + g * 4 + r], rp);
            }
        }
        #pragma unroll
        for (int n = 0; n < 4; ++n) {
            float cp = 0.f;
            #pragma unroll
            for (int m = 0; m < 8; ++m)
                #pragma unroll
                for (int r = 0; r < 4; ++r) cp += acc[m][n][r];
            cp += __shfl_xor(cp, 16, 64);
            cp += __shfl_xor(cp, 32, 64);
            if (g == 0) atomicAdd(&cs_l[wc * 64 + n * 16 + fr], cp);
        }
        __syncthreads();
        if (t < 256) {
            atomicAdd(&rs[rowBase + t], rs_l[t]);
            atomicAdd(&cs[colBase + t], cs_l[t]);
        }
    }
}

// ---------------- pass2: read stored bf16 sim fragments, exp, row/col sums (temp inline) ----------------
__global__ __launch_bounds__(256) void pass2_kernel(
    const uint4* __restrict__ simbuf, const float* __restrict__ scal, const int* __restrict__ num_pos_i,
    float* __restrict__ rs, float* __restrict__ cs)
{
    __shared__ float rs_l[128], cs_l[256];
    int q = blockIdx.x, rec = q >> 1, h = q & 1;
    int by = rec >> 4, bx = rec & 15;
    int rowBase = by * 256 + h * 128, colBase = bx * 256;
    int t = threadIdx.x, w4 = t >> 6, lane = t & 63;
    int gw = h * 4 + w4;                 // gemm wave id; wr = h, wc = w4
    int wc = gw & 3;
    int fr = lane & 15, g = lane >> 4;
    if (t < 128) rs_l[t] = 0.f;
    cs_l[t] = 0.f;
    __syncthreads();
    float invT = compute_invT(scal, num_pos_i);

    const uint4* base = simbuf + ((size_t)(rec * 8 + gw) * 16) * 64 + lane;
    uint4 u16[16];
    #pragma unroll
    for (int iv = 0; iv < 16; ++iv) u16[iv] = base[iv * 64];
    uint w32[64];
    #pragma unroll
    for (int iv = 0; iv < 16; ++iv) {
        w32[iv * 4]     = u16[iv].x; w32[iv * 4 + 1] = u16[iv].y;
        w32[iv * 4 + 2] = u16[iv].z; w32[iv * 4 + 3] = u16[iv].w;
    }

    float cp[4] = {0.f, 0.f, 0.f, 0.f};
    #pragma unroll
    for (int m = 0; m < 8; ++m) {
        float rp[4] = {0.f, 0.f, 0.f, 0.f};
        #pragma unroll
        for (int n = 0; n < 4; ++n)
            #pragma unroll
            for (int qq = 0; qq < 2; ++qq) {
                uint w = w32[2 * (m * 4 + n) + qq];
                float lo = __uint_as_float(w << 16);
                float hi = __uint_as_float(w & 0xffff0000u);
                float elo = __expf((lo - 1.0f) * invT);
                float ehi = __expf((hi - 1.0f) * invT);
                rp[qq * 2]     += elo;
                rp[qq * 2 + 1] += ehi;
                cp[n] += elo + ehi;
            }
        #pragma unroll
        for (int r = 0; r < 4; ++r) {
            float v = rp[r];
            v += __shfl_xor(v, 1, 64);
            v += __shfl_xor(v, 2, 64);
            v += __shfl_xor(v, 4, 64);
            v += __shfl_xor(v, 8, 64);
            if (fr == 0) atomicAdd(&rs_l[m * 16 + g * 4 + r], v);
        }
    }
    #pragma unroll
    for (int n = 0; n < 4; ++n) {
        float v = cp[n];
        v += __shfl_xor(v, 16, 64);
        v += __shfl_xor(v, 32, 64);
        if (g == 0) atomicAdd(&cs_l[wc * 64 + n * 16 + fr], v);
    }
    __syncthreads();
    if (t < 128) atomicAdd(&rs[rowBase + t], rs_l[t]);
    atomicAdd(&cs[colBase + t], cs_l[t]);
}

// ---------------- fallback temp kernel (non-store path only) ----------------
__global__ void temp_kernel(float* scal, const int* num_pos_i)
{
    scal[4] = compute_invT(scal, num_pos_i);
}

// ---------------- final loss (temp inline) ----------------
__global__ __launch_bounds__(256) void final_kernel(
    const float* __restrict__ scal, const int* __restrict__ num_pos_i,
    const float* __restrict__ rs, const float* __restrict__ cs,
    const float* __restrict__ cntf, float* __restrict__ out)
{
    int t = threadIdx.x;
    float a = 0.0f, npl = 0.0f;
    for (int i = t; i < NB; i += 256) {
        float c = cntf[i];
        a += c * (logf(rs[i]) + logf(cs[i]));
        npl += c;
    }
    #pragma unroll
    for (int off = 32; off > 0; off >>= 1) {
        a += __shfl_down(a, off, 64);
        npl += __shfl_down(npl, off, 64);
    }
    __shared__ float ra[4], rn[4];
    int wid = t >> 6, lane = t & 63;
    if (lane == 0) { ra[wid] = a; rn[wid] = npl; }
    __syncthreads();
    if (t == 0) {
        float A  = ra[0] + ra[1] + ra[2] + ra[3];
        float np = rn[0] + rn[1] + rn[2] + rn[3];
        float invT = compute_invT(scal, num_pos_i);
        float mf = scal[1];
        // lse_row[i] = 1/temp + log(rs[i]); v2t+t2v = sum cnt*(lse_r+lse_c) - 2*mf/temp
        float loss = (A + 2.0f * invT * (np - mf)) / (2.0f * np);
        out[0] = loss;
    }
}

extern "C" void kernel_launch(void* const* d_in, const int* in_sizes, int n_in,
                              void* d_out, int out_size, void* d_ws, size_t ws_size,
                              hipStream_t stream)
{
    const float* vf  = (const float*)d_in[0];
    const float* tf  = (const float*)d_in[1];
    const int*   ids = (const int*)d_in[2];

    float* ws_f = (float*)d_ws;
    float* scal = ws_f;                 // [0]=total [1]=S_mf [2]=trace [3]=unused [4]=1/temp(fallback) [5]=num_pos(int)
    float* rs   = ws_f + 16;            // 4096
    float* cs   = ws_f + 16 + 4096;     // 4096
    float* cntf = ws_f + 16 + 8192;     // 4096 (fully overwritten)
    int* num_pos = (int*)(scal + 5);
    __hip_bfloat16* vhat  = (__hip_bfloat16*)((char*)d_ws + 65536);
    __hip_bfloat16* that_ = vhat + (size_t)NB * DD;

    const size_t SIM_OFF = 16777216;    // vhat/that end at ~12.65 MB
    uint4* simbuf = (uint4*)((char*)d_ws + SIM_OFF);
    bool store = ws_size >= SIM_OFF + (size_t)NB * NB * 2;

    // re-zero accumulators each call (graph replays accumulate via atomics)
    hipMemsetAsync(d_ws, 0, (16 + 8192) * sizeof(float), stream);

    prep_kernel<<<2 * NB + NB / 256, 256, 0, stream>>>(vf, tf, ids, vhat, that_, cntf, num_pos);
    if (store) {
        gemm_kernel<0, true><<<256, 512, 0, stream>>>(vhat, that_, ids, scal, rs, cs, simbuf);
        pass2_kernel<<<512, 256, 0, stream>>>(simbuf, scal, num_pos, rs, cs);
    } else {
        gemm_kernel<0, false><<<256, 512, 0, stream>>>(vhat, that_, ids, scal, rs, cs, nullptr);
        temp_kernel<<<1, 1, 0, stream>>>(scal, num_pos);
        gemm_kernel<1, false><<<256, 512, 0, stream>>>(vhat, that_, ids, scal, rs, cs, nullptr);
    }
    final_kernel<<<1, 256, 0, stream>>>(scal, num_pos, rs, cs, cntf, (float*)d_out);
}

// Round 6
// 104.545 us; speedup vs baseline: 1.6464x; 1.0642x over previous
//
#include <hip/hip_runtime.h>
#include <hip/hip_bf16.h>

#define NB 4096
#define DD 768
#define NKT 24            // K-tiles of BK=32: 768/32

typedef __bf16 bf16x8 __attribute__((ext_vector_type(8)));
typedef float f32x4 __attribute__((ext_vector_type(4)));
typedef unsigned int uint;
typedef uint u32x4 __attribute__((ext_vector_type(4)));

#define WAITVM(N) asm volatile("s_waitcnt vmcnt(" #N ")" ::: "memory")
#define WAITLGKM0 asm volatile("s_waitcnt lgkmcnt(0)" ::: "memory")

// ---------------- temp from global stats (race-free: np from 16 partials) ----------------
__device__ __forceinline__ float compute_invT(const float* scal, const int* npart)
{
    int npi = 0;
    #pragma unroll
    for (int i = 0; i < 16; ++i) npi += npart[i];
    float total = scal[0], mf = scal[1], trace = scal[2];
    float np = (float)npi;
    float pos_cnt = np - (float)NB;
    float neg_cnt = (float)NB * (float)NB - np;
    float pos_mean = (mf - trace) / fmaxf(1.0f, pos_cnt);
    float neg_mean = (total - mf) / fmaxf(1.0f, neg_cnt);
    float sep = pos_mean - neg_mean;
    float temp = 0.07f * (0.8f + 0.4f * expf(-2.0f * sep));
    temp = fminf(fmaxf(temp, 0.04f), 0.2f);
    return 1.0f / temp;
}

// ---------------- prep: blocks 0..2047 normalize (1 wave = 1 row, float4); 2048..2063 cnt ----------------
__global__ __launch_bounds__(256) void prep_kernel(
    const float* __restrict__ vf, const float* __restrict__ tf, const int* __restrict__ ids,
    __hip_bfloat16* __restrict__ vhat, __hip_bfloat16* __restrict__ that_,
    float* __restrict__ cntf, int* __restrict__ npart, float* __restrict__ scal)
{
    int b = blockIdx.x;
    int t = threadIdx.x, wid = t >> 6, lane = t & 63;
    if (b < 2048) {
        int row = b * 4 + wid;
        const float* src;
        __hip_bfloat16* dst;
        if (row < NB) { src = vf + (size_t)row * DD; dst = vhat + (size_t)row * DD; }
        else          { src = tf + (size_t)(row - NB) * DD; dst = that_ + (size_t)(row - NB) * DD; }
        float4 x[3];
        #pragma unroll
        for (int c = 0; c < 3; ++c)
            x[c] = *(const float4*)(src + c * 256 + lane * 4);
        float s = 0.f;
        #pragma unroll
        for (int c = 0; c < 3; ++c)
            s += x[c].x * x[c].x + x[c].y * x[c].y + x[c].z * x[c].z + x[c].w * x[c].w;
        #pragma unroll
        for (int off = 1; off < 64; off <<= 1) s += __shfl_xor(s, off, 64);
        float scale = 1.0f / sqrtf(s);
        #pragma unroll
        for (int c = 0; c < 3; ++c) {
            ushort4 o;
            o.x = __builtin_bit_cast(unsigned short, __float2bfloat16(x[c].x * scale));
            o.y = __builtin_bit_cast(unsigned short, __float2bfloat16(x[c].y * scale));
            o.z = __builtin_bit_cast(unsigned short, __float2bfloat16(x[c].z * scale));
            o.w = __builtin_bit_cast(unsigned short, __float2bfloat16(x[c].w * scale));
            *(ushort4*)((unsigned short*)dst + c * 256 + lane * 4) = o;
        }
    } else {
        int blk = b - 2048;
        if (blk == 0 && t < 16) scal[t] = 0.0f;   // zero stats (gemm is a later dispatch)
        __shared__ int sh[512];
        __shared__ int wred[4];
        int i = blk * 256 + t;
        int my = ids[i];
        int c = 0;
        for (int base = 0; base < NB; base += 512) {
            sh[t]       = ids[base + t];
            sh[t + 256] = ids[base + t + 256];
            __syncthreads();
            #pragma unroll 16
            for (int j = 0; j < 512; ++j) c += (sh[j] == my);
            __syncthreads();
        }
        cntf[i] = (float)c;
        int cs_ = c;
        #pragma unroll
        for (int off = 32; off > 0; off >>= 1) cs_ += __shfl_down(cs_, off, 64);
        if (lane == 0) wred[wid] = cs_;
        __syncthreads();
        if (t == 0) npart[blk] = wred[0] + wred[1] + wred[2] + wred[3];
    }
}

// ---------------- staging: one K-tile unit = A[256][32] + B[256][32] (32 KB) ----------------
// Swizzle (both sides, rule #21): logical chunk c (16B) of row r at phys chunk c ^ ((r>>1)&3).
// global_load_lds dest is linear (base+lane*16); lane's global source chunk = (lane&3)^((lane>>3)&3).
// R2 measured this scheme at 0 bank conflicts (2-way aliasing = free, m136).
__device__ __forceinline__ void stage_range(
    __hip_bfloat16* ldsAll,
    const __hip_bfloat16* __restrict__ vhat, const __hip_bfloat16* __restrict__ that_,
    int rowBase, int colBase, int T, int i0, int i1, int wid, int lane)
{
    int u = T & 3;
    int k0 = T * 32;
    const __hip_bfloat16* src = (wid >= 4) ? that_ : vhat;
    int tb = (wid >= 4) ? colBase : rowBase;
    int w4 = wid & 3;
    int logc = (lane & 3) ^ ((lane >> 3) & 3);
    int rowIn = w4 * 64 + (lane >> 2);
    __hip_bfloat16* dbase = ldsAll + u * 16384 + ((wid >= 4) ? 8192 : 0) + w4 * 2048;
    #pragma unroll
    for (int i = i0; i <= i1; ++i) {
        const __hip_bfloat16* g = src + (size_t)(tb + rowIn + i * 16) * DD + k0 + logc * 8;
        __builtin_amdgcn_global_load_lds(
            (const __attribute__((address_space(1))) void*)g,
            (__attribute__((address_space(3))) void*)(dbase + i * 512),
            16, 0, 0);
    }
}

// ---------------- GEMM: 256x256 tile, 8 waves (2M x 4N), BK=32, 4-deep ring ----------------
template <int MODE, bool STORE>
__global__ __launch_bounds__(512, 2) void gemm_kernel(
    const __hip_bfloat16* __restrict__ vhat, const __hip_bfloat16* __restrict__ that_,
    const int* __restrict__ ids, float* __restrict__ scal,
    float* __restrict__ rs, float* __restrict__ cs, u32x4* __restrict__ simbuf)
{
    __shared__ __hip_bfloat16 ldsAll[4 * 16384];   // 128 KB: 4 ring units
    __shared__ int idr[256], idc[256];
    __shared__ float red[24];
    __shared__ float rs_l[256], cs_l[256];

    // XCD-chunked bijective swizzle: 8 regions of 4by x 8bx (grid 256 = 16x16)
    int bid = blockIdx.x;
    int rg = bid & 7, sq = bid >> 3;
    int by = (rg >> 1) * 4 + (sq >> 3);
    int bx = (rg & 1) * 8 + (sq & 7);
    int rowBase = by * 256, colBase = bx * 256;

    int t = threadIdx.x;
    int wid = t >> 6, lane = t & 63;
    int wr = wid >> 2, wc = wid & 3;         // wave = 128-row x 64-col output block
    int fr = lane & 15, g = lane >> 4;

    if (MODE == 0) {
        // zero rs/cs for the later pass (plain stores; consumed only by later dispatches)
        if (bx == 0 && t < 256) rs[rowBase + t] = 0.0f;
        if (by == 0 && t < 256) cs[colBase + t] = 0.0f;
    } else {
        if (t < 256) { rs_l[t] = 0.0f; cs_l[t] = 0.0f; }
    }

    f32x4 acc[8][4];
    #pragma unroll
    for (int m = 0; m < 8; ++m)
        #pragma unroll
        for (int n = 0; n < 4; ++n) acc[m][n] = (f32x4){0.f, 0.f, 0.f, 0.f};

    // LDS read offsets (bf16 elems): phys chunk = g ^ ((row>>1)&3); row bits 1-2 from fr.
    int pcoff = ((g ^ ((fr >> 1) & 3)) * 8);
    int aoff = (wr * 128 + fr) * 32 + pcoff;
    int boff = 8192 + (wc * 64 + fr) * 32 + pcoff;

    // prologue: stage tiles 0,1,2 (12 loads/thread); tile0 complete -> vmcnt(8)
    stage_range(ldsAll, vhat, that_, rowBase, colBase, 0, 0, 3, wid, lane);
    stage_range(ldsAll, vhat, that_, rowBase, colBase, 1, 0, 3, wid, lane);
    stage_range(ldsAll, vhat, that_, rowBase, colBase, 2, 0, 3, wid, lane);
    WAITVM(8);
    __builtin_amdgcn_s_barrier();

    for (int T = 0; T < NKT; ++T) {
        const __hip_bfloat16* U = ldsAll + (T & 3) * 16384;
        // ======== phase A: reads(a0,bb) || stage half1(T+3) -> BAR -> MFMA m0..3 ========
        bf16x8 a0[4], bb[4];
        #pragma unroll
        for (int m = 0; m < 4; ++m) a0[m] = *(const bf16x8*)(U + aoff + m * 512);
        #pragma unroll
        for (int n = 0; n < 4; ++n) bb[n] = *(const bf16x8*)(U + boff + n * 512);
        if (T + 3 < NKT)
            stage_range(ldsAll, vhat, that_, rowBase, colBase, T + 3, 0, 1, wid, lane);
        __builtin_amdgcn_sched_barrier(0);
        __builtin_amdgcn_s_barrier();
        WAITLGKM0;
        __builtin_amdgcn_sched_barrier(0);
        __builtin_amdgcn_s_setprio(1);
        #pragma unroll
        for (int m = 0; m < 4; ++m)
            #pragma unroll
            for (int n = 0; n < 4; ++n)
                acc[m][n] = __builtin_amdgcn_mfma_f32_16x16x32_bf16(a0[m], bb[n], acc[m][n], 0, 0, 0);
        __builtin_amdgcn_s_setprio(0);
        __builtin_amdgcn_sched_barrier(0);
        __builtin_amdgcn_s_barrier();
        // ======== phase B: reads(a1) || stage half2(T+3) -> BAR -> MFMA m4..7 ========
        bf16x8 a1[4];
        #pragma unroll
        for (int m = 0; m < 4; ++m) a1[m] = *(const bf16x8*)(U + aoff + (m + 4) * 512);
        if (T + 3 < NKT)
            stage_range(ldsAll, vhat, that_, rowBase, colBase, T + 3, 2, 3, wid, lane);
        __builtin_amdgcn_sched_barrier(0);
        __builtin_amdgcn_s_barrier();
        WAITLGKM0;
        __builtin_amdgcn_sched_barrier(0);
        __builtin_amdgcn_s_setprio(1);
        #pragma unroll
        for (int m = 0; m < 4; ++m)
            #pragma unroll
            for (int n = 0; n < 4; ++n)
                acc[m + 4][n] = __builtin_amdgcn_mfma_f32_16x16x32_bf16(a1[m], bb[n], acc[m + 4][n], 0, 0, 0);
        __builtin_amdgcn_s_setprio(0);
        __builtin_amdgcn_sched_barrier(0);
        // ---- tile boundary: T+1 staged; keep T+2/T+3 in flight (never vmcnt 0 mid-loop) ----
        if (T < NKT - 3)       { WAITVM(8); }
        else if (T == NKT - 3) { WAITVM(4); }
        else if (T == NKT - 2) { WAITVM(0); }
        __builtin_amdgcn_s_barrier();
    }

    // C/D layout per frag: col = fr, row = g*4 + reg   [m89-verified]
    if (MODE == 0) {
        // ---- store sim FIRST (nontemporal, drains under the stats reduction) ----
        if (STORE) {
            int rec = by * 16 + bx;           // logical tile id (swizzle-independent)
            u32x4* dst = simbuf + ((size_t)(rec * 8 + wid) * 16) * 64 + lane;
            uint w32[64];
            #pragma unroll
            for (int m = 0; m < 8; ++m)
                #pragma unroll
                for (int n = 0; n < 4; ++n)
                    #pragma unroll
                    for (int qq = 0; qq < 2; ++qq) {
                        unsigned short u0 = __builtin_bit_cast(unsigned short,
                            __float2bfloat16(acc[m][n][qq * 2]));
                        unsigned short u1 = __builtin_bit_cast(unsigned short,
                            __float2bfloat16(acc[m][n][qq * 2 + 1]));
                        w32[2 * (m * 4 + n) + qq] = (uint)u0 | ((uint)u1 << 16);
                    }
            #pragma unroll
            for (int iv = 0; iv < 16; ++iv) {
                u32x4 val = { w32[iv * 4], w32[iv * 4 + 1], w32[iv * 4 + 2], w32[iv * 4 + 3] };
                __builtin_nontemporal_store(val, dst + iv * 64);
            }
        }
        if (t < 256) idr[t] = ids[rowBase + t];
        else         idc[t - 256] = ids[colBase + (t - 256)];
        __syncthreads();
        float tsum = 0.f, msum = 0.f, dsum = 0.f;
        #pragma unroll
        for (int m = 0; m < 8; ++m) {
            int rl = wr * 128 + m * 16 + g * 4;
            #pragma unroll
            for (int n = 0; n < 4; ++n) {
                int cl = wc * 64 + n * 16 + fr;
                int colId = idc[cl];
                int gj = colBase + cl;
                #pragma unroll
                for (int r = 0; r < 4; ++r) {
                    float val = acc[m][n][r];
                    tsum += val;
                    if (idr[rl + r] == colId) msum += val;
                    if (rowBase + rl + r == gj) dsum += val;
                }
            }
        }
        #pragma unroll
        for (int off = 32; off > 0; off >>= 1) {
            tsum += __shfl_down(tsum, off, 64);
            msum += __shfl_down(msum, off, 64);
            dsum += __shfl_down(dsum, off, 64);
        }
        if (lane == 0) { red[wid] = tsum; red[8 + wid] = msum; red[16 + wid] = dsum; }
        __syncthreads();
        if (t == 0) {
            float s0 = 0.f, s1 = 0.f, s2 = 0.f;
            #pragma unroll
            for (int w = 0; w < 8; ++w) { s0 += red[w]; s1 += red[8 + w]; s2 += red[16 + w]; }
            atomicAdd(&scal[0], s0);
            atomicAdd(&scal[1], s1);
            atomicAdd(&scal[2], s2);
        }
    } else {
        float invT = scal[4];
        #pragma unroll
        for (int m = 0; m < 8; ++m)
            #pragma unroll
            for (int n = 0; n < 4; ++n)
                #pragma unroll
                for (int r = 0; r < 4; ++r)
                    acc[m][n][r] = __expf((acc[m][n][r] - 1.0f) * invT);
        #pragma unroll
        for (int m = 0; m < 8; ++m) {
            #pragma unroll
            for (int r = 0; r < 4; ++r) {
                float rp = 0.f;
                #pragma unroll
                for (int n = 0; n < 4; ++n) rp += acc[m][n][r];
                rp += __shfl_xor(rp, 1, 64);
                rp += __shfl_xor(rp, 2, 64);
                rp += __shfl_xor(rp, 4, 64);
                rp += __shfl_xor(rp, 8, 64);
                if (fr == 0) atomicAdd(&rs_l[wr * 128 + m * 16 + g * 4 + r], rp);
            }
        }
        #pragma unroll
        for (int n = 0; n < 4; ++n) {
            float cp = 0.f;
            #pragma unroll
            for (int m = 0; m < 8; ++m)
                #pragma unroll
                for (int r = 0; r < 4; ++r) cp += acc[m][n][r];
            cp += __shfl_xor(cp, 16, 64);
            cp += __shfl_xor(cp, 32, 64);
            if (g == 0) atomicAdd(&cs_l[wc * 64 + n * 16 + fr], cp);
        }
        __syncthreads();
        if (t < 256) {
            atomicAdd(&rs[rowBase + t], rs_l[t]);
            atomicAdd(&cs[colBase + t], cs_l[t]);
        }
    }
}

// ---------------- pass2: read stored bf16 sim fragments, exp, row/col sums (temp inline) ----------------
__global__ __launch_bounds__(256) void pass2_kernel(
    const u32x4* __restrict__ simbuf, const float* __restrict__ scal, const int* __restrict__ npart,
    float* __restrict__ rs, float* __restrict__ cs)
{
    __shared__ float rs_l[128], cs_l[256];
    int q = blockIdx.x, rec = q >> 1, h = q & 1;
    int by = rec >> 4, bx = rec & 15;
    int rowBase = by * 256 + h * 128, colBase = bx * 256;
    int t = threadIdx.x, w4 = t >> 6, lane = t & 63;
    int gw = h * 4 + w4;                 // gemm wave id; wr = h, wc = w4
    int wc = gw & 3;
    int fr = lane & 15, g = lane >> 4;
    if (t < 128) rs_l[t] = 0.f;
    cs_l[t] = 0.f;
    __syncthreads();
    float invT = compute_invT(scal, npart);

    const u32x4* base = simbuf + ((size_t)(rec * 8 + gw) * 16) * 64 + lane;
    u32x4 u16[16];
    #pragma unroll
    for (int iv = 0; iv < 16; ++iv) u16[iv] = __builtin_nontemporal_load(base + iv * 64);
    uint w32[64];
    #pragma unroll
    for (int iv = 0; iv < 16; ++iv) {
        w32[iv * 4]     = u16[iv].x; w32[iv * 4 + 1] = u16[iv].y;
        w32[iv * 4 + 2] = u16[iv].z; w32[iv * 4 + 3] = u16[iv].w;
    }

    float cp[4] = {0.f, 0.f, 0.f, 0.f};
    #pragma unroll
    for (int m = 0; m < 8; ++m) {
        float rp[4] = {0.f, 0.f, 0.f, 0.f};
        #pragma unroll
        for (int n = 0; n < 4; ++n)
            #pragma unroll
            for (int qq = 0; qq < 2; ++qq) {
                uint w = w32[2 * (m * 4 + n) + qq];
                float lo = __uint_as_float(w << 16);
                float hi = __uint_as_float(w & 0xffff0000u);
                float elo = __expf((lo - 1.0f) * invT);
                float ehi = __expf((hi - 1.0f) * invT);
                rp[qq * 2]     += elo;
                rp[qq * 2 + 1] += ehi;
                cp[n] += elo + ehi;
            }
        #pragma unroll
        for (int r = 0; r < 4; ++r) {
            float v = rp[r];
            v += __shfl_xor(v, 1, 64);
            v += __shfl_xor(v, 2, 64);
            v += __shfl_xor(v, 4, 64);
            v += __shfl_xor(v, 8, 64);
            if (fr == 0) atomicAdd(&rs_l[m * 16 + g * 4 + r], v);
        }
    }
    #pragma unroll
    for (int n = 0; n < 4; ++n) {
        float v = cp[n];
        v += __shfl_xor(v, 16, 64);
        v += __shfl_xor(v, 32, 64);
        if (g == 0) atomicAdd(&cs_l[wc * 64 + n * 16 + fr], v);
    }
    __syncthreads();
    if (t < 128) atomicAdd(&rs[rowBase + t], rs_l[t]);
    atomicAdd(&cs[colBase + t], cs_l[t]);
}

// ---------------- fallback temp kernel (non-store path only) ----------------
__global__ void temp_kernel(float* scal, const int* npart)
{
    scal[4] = compute_invT(scal, npart);
}

// ---------------- final loss (temp inline) ----------------
__global__ __launch_bounds__(256) void final_kernel(
    const float* __restrict__ scal, const int* __restrict__ npart,
    const float* __restrict__ rs, const float* __restrict__ cs,
    const float* __restrict__ cntf, float* __restrict__ out)
{
    int t = threadIdx.x;
    float a = 0.0f, npl = 0.0f;
    for (int i = t; i < NB; i += 256) {
        float c = cntf[i];
        a += c * (logf(rs[i]) + logf(cs[i]));
        npl += c;
    }
    #pragma unroll
    for (int off = 32; off > 0; off >>= 1) {
        a += __shfl_down(a, off, 64);
        npl += __shfl_down(npl, off, 64);
    }
    __shared__ float ra[4], rn[4];
    int wid = t >> 6, lane = t & 63;
    if (lane == 0) { ra[wid] = a; rn[wid] = npl; }
    __syncthreads();
    if (t == 0) {
        float A  = ra[0] + ra[1] + ra[2] + ra[3];
        float np = rn[0] + rn[1] + rn[2] + rn[3];
        float invT = compute_invT(scal, npart);
        float mf = scal[1];
        // lse_row[i] = 1/temp + log(rs[i]); v2t+t2v = sum cnt*(lse_r+lse_c) - 2*mf/temp
        float loss = (A + 2.0f * invT * (np - mf)) / (2.0f * np);
        out[0] = loss;
    }
}

extern "C" void kernel_launch(void* const* d_in, const int* in_sizes, int n_in,
                              void* d_out, int out_size, void* d_ws, size_t ws_size,
                              hipStream_t stream)
{
    const float* vf  = (const float*)d_in[0];
    const float* tf  = (const float*)d_in[1];
    const int*   ids = (const int*)d_in[2];

    float* ws_f = (float*)d_ws;
    float* scal = ws_f;                 // [0]=total [1]=S_mf [2]=trace [4]=invT(fallback)
    float* rs   = ws_f + 16;            // 4096
    float* cs   = ws_f + 16 + 4096;     // 4096
    float* cntf = ws_f + 16 + 8192;     // 4096 (fully overwritten)
    int* npart  = (int*)(ws_f + 16 + 12288);   // 16 partial num_pos counts
    __hip_bfloat16* vhat  = (__hip_bfloat16*)((char*)d_ws + 65536);
    __hip_bfloat16* that_ = vhat + (size_t)NB * DD;

    const size_t SIM_OFF = 16777216;    // vhat/that end at ~12.65 MB
    u32x4* simbuf = (u32x4*)((char*)d_ws + SIM_OFF);
    bool store = ws_size >= SIM_OFF + (size_t)NB * NB * 2;

    // no memset: scal zeroed by prep block; rs/cs zeroed inside gemm<0>; npart/cntf plain-stored

    prep_kernel<<<2064, 256, 0, stream>>>(vf, tf, ids, vhat, that_, cntf, npart, scal);
    if (store) {
        gemm_kernel<0, true><<<256, 512, 0, stream>>>(vhat, that_, ids, scal, rs, cs, simbuf);
        pass2_kernel<<<512, 256, 0, stream>>>(simbuf, scal, npart, rs, cs);
    } else {
        gemm_kernel<0, false><<<256, 512, 0, stream>>>(vhat, that_, ids, scal, rs, cs, nullptr);
        temp_kernel<<<1, 1, 0, stream>>>(scal, npart);
        gemm_kernel<1, false><<<256, 512, 0, stream>>>(vhat, that_, ids, scal, rs, cs, nullptr);
    }
    final_kernel<<<1, 256, 0, stream>>>(scal, npart, rs, cs, cntf, (float*)d_out);
}

// Round 7
// 102.463 us; speedup vs baseline: 1.6798x; 1.0203x over previous
//
#include <hip/hip_runtime.h>
#include <hip/hip_bf16.h>

#define NB 4096
#define DD 768
#define NKT 24            // K-tiles of BK=32: 768/32
#define NBLK 256          // gemm grid: 256 blocks = 1 per CU (128KB LDS forces 1/CU)

typedef __bf16 bf16x8 __attribute__((ext_vector_type(8)));
typedef float f32x4 __attribute__((ext_vector_type(4)));
typedef unsigned int uint;

#define WAITVM(N) asm volatile("s_waitcnt vmcnt(" #N ")" ::: "memory")
#define WAITLGKM0 asm volatile("s_waitcnt lgkmcnt(0)" ::: "memory")

// ---------------- temp from stats; npart via plain loads (prep is a prior dispatch) ----------------
__device__ __forceinline__ float invT_from(float total, float mf, float trace, const int* npart)
{
    int npi = 0;
    #pragma unroll
    for (int i = 0; i < 16; ++i) npi += npart[i];
    float np = (float)npi;
    float pos_cnt = np - (float)NB;
    float neg_cnt = (float)NB * (float)NB - np;
    float pos_mean = (mf - trace) / fmaxf(1.0f, pos_cnt);
    float neg_mean = (total - mf) / fmaxf(1.0f, neg_cnt);
    float sep = pos_mean - neg_mean;
    float temp = 0.07f * (0.8f + 0.4f * expf(-2.0f * sep));
    temp = fminf(fmaxf(temp, 0.04f), 0.2f);
    return 1.0f / temp;
}

// ---------------- prep: 0..2047 normalize (1 wave = 1 row, float4); 2048..2063 cnt; 2064..2095 zero rs/cs ----------------
__global__ __launch_bounds__(256) void prep_kernel(
    const float* __restrict__ vf, const float* __restrict__ tf, const int* __restrict__ ids,
    __hip_bfloat16* __restrict__ vhat, __hip_bfloat16* __restrict__ that_,
    float* __restrict__ cntf, int* __restrict__ npart, float* __restrict__ scal,
    float* __restrict__ rscs)
{
    int b = blockIdx.x;
    int t = threadIdx.x, wid = t >> 6, lane = t & 63;
    if (b < 2048) {
        int row = b * 4 + wid;
        const float* src;
        __hip_bfloat16* dst;
        if (row < NB) { src = vf + (size_t)row * DD; dst = vhat + (size_t)row * DD; }
        else          { src = tf + (size_t)(row - NB) * DD; dst = that_ + (size_t)(row - NB) * DD; }
        float4 x[3];
        #pragma unroll
        for (int c = 0; c < 3; ++c)
            x[c] = *(const float4*)(src + c * 256 + lane * 4);
        float s = 0.f;
        #pragma unroll
        for (int c = 0; c < 3; ++c)
            s += x[c].x * x[c].x + x[c].y * x[c].y + x[c].z * x[c].z + x[c].w * x[c].w;
        #pragma unroll
        for (int off = 1; off < 64; off <<= 1) s += __shfl_xor(s, off, 64);
        float scale = 1.0f / sqrtf(s);
        #pragma unroll
        for (int c = 0; c < 3; ++c) {
            ushort4 o;
            o.x = __builtin_bit_cast(unsigned short, __float2bfloat16(x[c].x * scale));
            o.y = __builtin_bit_cast(unsigned short, __float2bfloat16(x[c].y * scale));
            o.z = __builtin_bit_cast(unsigned short, __float2bfloat16(x[c].z * scale));
            o.w = __builtin_bit_cast(unsigned short, __float2bfloat16(x[c].w * scale));
            *(ushort4*)((unsigned short*)dst + c * 256 + lane * 4) = o;
        }
    } else if (b < 2064) {
        int blk = b - 2048;
        if (blk == 0 && t < 16) scal[t] = 0.0f;   // zeroes stats + the grid-barrier counter
        __shared__ int sh[512];
        __shared__ int wred[4];
        int i = blk * 256 + t;
        int my = ids[i];
        int c = 0;
        for (int base = 0; base < NB; base += 512) {
            sh[t]       = ids[base + t];
            sh[t + 256] = ids[base + t + 256];
            __syncthreads();
            #pragma unroll 16
            for (int j = 0; j < 512; ++j) c += (sh[j] == my);
            __syncthreads();
        }
        cntf[i] = (float)c;
        int cs_ = c;
        #pragma unroll
        for (int off = 32; off > 0; off >>= 1) cs_ += __shfl_down(cs_, off, 64);
        if (lane == 0) wred[wid] = cs_;
        __syncthreads();
        if (t == 0) npart[blk] = wred[0] + wred[1] + wred[2] + wred[3];
    } else {
        // zero rs (4096) + cs (4096), contiguous
        rscs[(b - 2064) * 256 + t] = 0.0f;
    }
}

// ---------------- staging: one K-tile unit = A[256][32] + B[256][32] (32 KB) ----------------
// Swizzle (both sides, rule #21): logical chunk c (16B) of row r at phys chunk c ^ ((r>>1)&3).
// global_load_lds dest is linear (base+lane*16); lane's global source chunk = (lane&3)^((lane>>3)&3).
// R2 measured this scheme at 0 bank conflicts (2-way aliasing = free, m136).
__device__ __forceinline__ void stage_range(
    __hip_bfloat16* ldsAll,
    const __hip_bfloat16* __restrict__ vhat, const __hip_bfloat16* __restrict__ that_,
    int rowBase, int colBase, int T, int i0, int i1, int wid, int lane)
{
    int u = T & 3;
    int k0 = T * 32;
    const __hip_bfloat16* src = (wid >= 4) ? that_ : vhat;
    int tb = (wid >= 4) ? colBase : rowBase;
    int w4 = wid & 3;
    int logc = (lane & 3) ^ ((lane >> 3) & 3);
    int rowIn = w4 * 64 + (lane >> 2);
    __hip_bfloat16* dbase = ldsAll + u * 16384 + ((wid >= 4) ? 8192 : 0) + w4 * 2048;
    #pragma unroll
    for (int i = i0; i <= i1; ++i) {
        const __hip_bfloat16* g = src + (size_t)(tb + rowIn + i * 16) * DD + k0 + logc * 8;
        __builtin_amdgcn_global_load_lds(
            (const __attribute__((address_space(1))) void*)g,
            (__attribute__((address_space(3))) void*)(dbase + i * 512),
            16, 0, 0);
    }
}

// ---------------- fused GEMM + stats + grid-barrier + exp row/col sums ----------------
// 256x256 tile, 8 waves (2M x 4N), BK=32, 4-deep ring. Grid barrier is safe: grid=256,
// 1 block/CU (128KB LDS), so every spinning block owns a distinct CU and the last block
// always finds a free CU -> all co-resident.
__global__ __launch_bounds__(512, 2) void fused_kernel(
    const __hip_bfloat16* __restrict__ vhat, const __hip_bfloat16* __restrict__ that_,
    const int* __restrict__ ids, float* __restrict__ scal,
    float* __restrict__ rs, float* __restrict__ cs, const int* __restrict__ npart,
    uint* __restrict__ bar)
{
    __shared__ __hip_bfloat16 ldsAll[4 * 16384];   // 128 KB: 4 ring units
    __shared__ int idr[256], idc[256];
    __shared__ float red[24];
    __shared__ float rs_l[256], cs_l[256];
    __shared__ float invT_sh;

    // XCD-chunked bijective swizzle: 8 regions of 4by x 8bx (grid 256 = 16x16)
    int bid = blockIdx.x;
    int rg = bid & 7, sq = bid >> 3;
    int by = (rg >> 1) * 4 + (sq >> 3);
    int bx = (rg & 1) * 8 + (sq & 7);
    int rowBase = by * 256, colBase = bx * 256;

    int t = threadIdx.x;
    int wid = t >> 6, lane = t & 63;
    int wr = wid >> 2, wc = wid & 3;         // wave = 128-row x 64-col output block
    int fr = lane & 15, g = lane >> 4;

    f32x4 acc[8][4];
    #pragma unroll
    for (int m = 0; m < 8; ++m)
        #pragma unroll
        for (int n = 0; n < 4; ++n) acc[m][n] = (f32x4){0.f, 0.f, 0.f, 0.f};

    // LDS read offsets (bf16 elems): phys chunk = g ^ ((row>>1)&3); row bits 1-2 from fr.
    int pcoff = ((g ^ ((fr >> 1) & 3)) * 8);
    int aoff = (wr * 128 + fr) * 32 + pcoff;
    int boff = 8192 + (wc * 64 + fr) * 32 + pcoff;

    // prologue: stage tiles 0,1,2 (12 loads/thread); tile0 complete -> vmcnt(8)
    stage_range(ldsAll, vhat, that_, rowBase, colBase, 0, 0, 3, wid, lane);
    stage_range(ldsAll, vhat, that_, rowBase, colBase, 1, 0, 3, wid, lane);
    stage_range(ldsAll, vhat, that_, rowBase, colBase, 2, 0, 3, wid, lane);
    WAITVM(8);
    __builtin_amdgcn_s_barrier();

    for (int T = 0; T < NKT; ++T) {
        const __hip_bfloat16* U = ldsAll + (T & 3) * 16384;
        // ======== phase A: reads(a0,bb) || stage half1(T+3) -> BAR -> MFMA m0..3 ========
        bf16x8 a0[4], bb[4];
        #pragma unroll
        for (int m = 0; m < 4; ++m) a0[m] = *(const bf16x8*)(U + aoff + m * 512);
        #pragma unroll
        for (int n = 0; n < 4; ++n) bb[n] = *(const bf16x8*)(U + boff + n * 512);
        if (T + 3 < NKT)
            stage_range(ldsAll, vhat, that_, rowBase, colBase, T + 3, 0, 1, wid, lane);
        __builtin_amdgcn_sched_barrier(0);
        __builtin_amdgcn_s_barrier();
        WAITLGKM0;
        __builtin_amdgcn_sched_barrier(0);
        __builtin_amdgcn_s_setprio(1);
        #pragma unroll
        for (int m = 0; m < 4; ++m)
            #pragma unroll
            for (int n = 0; n < 4; ++n)
                acc[m][n] = __builtin_amdgcn_mfma_f32_16x16x32_bf16(a0[m], bb[n], acc[m][n], 0, 0, 0);
        __builtin_amdgcn_s_setprio(0);
        __builtin_amdgcn_sched_barrier(0);
        __builtin_amdgcn_s_barrier();
        // ======== phase B: reads(a1) || stage half2(T+3) -> BAR -> MFMA m4..7 ========
        bf16x8 a1[4];
        #pragma unroll
        for (int m = 0; m < 4; ++m) a1[m] = *(const bf16x8*)(U + aoff + (m + 4) * 512);
        if (T + 3 < NKT)
            stage_range(ldsAll, vhat, that_, rowBase, colBase, T + 3, 2, 3, wid, lane);
        __builtin_amdgcn_sched_barrier(0);
        __builtin_amdgcn_s_barrier();
        WAITLGKM0;
        __builtin_amdgcn_sched_barrier(0);
        __builtin_amdgcn_s_setprio(1);
        #pragma unroll
        for (int m = 0; m < 4; ++m)
            #pragma unroll
            for (int n = 0; n < 4; ++n)
                acc[m + 4][n] = __builtin_amdgcn_mfma_f32_16x16x32_bf16(a1[m], bb[n], acc[m + 4][n], 0, 0, 0);
        __builtin_amdgcn_s_setprio(0);
        __builtin_amdgcn_sched_barrier(0);
        // ---- tile boundary: T+1 staged; keep T+2/T+3 in flight (never vmcnt 0 mid-loop) ----
        if (T < NKT - 3)       { WAITVM(8); }
        else if (T == NKT - 3) { WAITVM(4); }
        else if (T == NKT - 2) { WAITVM(0); }
        __builtin_amdgcn_s_barrier();
    }

    // ======== stats: {total, S_mf, trace} ======== C/D: col=fr, row=g*4+reg [m89-verified]
    if (t < 256) idr[t] = ids[rowBase + t];
    else         idc[t - 256] = ids[colBase + (t - 256)];
    __syncthreads();
    float tsum = 0.f, msum = 0.f, dsum = 0.f;
    #pragma unroll
    for (int m = 0; m < 8; ++m) {
        int rl = wr * 128 + m * 16 + g * 4;
        #pragma unroll
        for (int n = 0; n < 4; ++n) {
            int cl = wc * 64 + n * 16 + fr;
            int colId = idc[cl];
            int gj = colBase + cl;
            #pragma unroll
            for (int r = 0; r < 4; ++r) {
                float val = acc[m][n][r];
                tsum += val;
                if (idr[rl + r] == colId) msum += val;
                if (rowBase + rl + r == gj) dsum += val;
            }
        }
    }
    #pragma unroll
    for (int off = 32; off > 0; off >>= 1) {
        tsum += __shfl_down(tsum, off, 64);
        msum += __shfl_down(msum, off, 64);
        dsum += __shfl_down(dsum, off, 64);
    }
    if (lane == 0) { red[wid] = tsum; red[8 + wid] = msum; red[16 + wid] = dsum; }
    __syncthreads();
    if (t == 0) {
        float s0 = 0.f, s1 = 0.f, s2 = 0.f;
        #pragma unroll
        for (int w = 0; w < 8; ++w) { s0 += red[w]; s1 += red[8 + w]; s2 += red[16 + w]; }
        atomicAdd(&scal[0], s0);
        atomicAdd(&scal[1], s1);
        atomicAdd(&scal[2], s2);
    }

    // ======== grid barrier (arrive + spin; device-scope, acq_rel) ========
    __syncthreads();
    if (t == 0) {
        __hip_atomic_fetch_add(bar, 1u, __ATOMIC_ACQ_REL, __HIP_MEMORY_SCOPE_AGENT);
        while (__hip_atomic_load(bar, __ATOMIC_ACQUIRE, __HIP_MEMORY_SCOPE_AGENT) < NBLK) { }
        float total = __hip_atomic_load(&scal[0], __ATOMIC_RELAXED, __HIP_MEMORY_SCOPE_AGENT);
        float mf    = __hip_atomic_load(&scal[1], __ATOMIC_RELAXED, __HIP_MEMORY_SCOPE_AGENT);
        float trace = __hip_atomic_load(&scal[2], __ATOMIC_RELAXED, __HIP_MEMORY_SCOPE_AGENT);
        invT_sh = invT_from(total, mf, trace, npart);
    }
    if (t < 256) { rs_l[t] = 0.0f; cs_l[t] = 0.0f; }
    __syncthreads();
    float invT = invT_sh;

    // ======== exp((sim-1)/temp) row & col sums, straight from registers ========
    #pragma unroll
    for (int m = 0; m < 8; ++m)
        #pragma unroll
        for (int n = 0; n < 4; ++n)
            #pragma unroll
            for (int r = 0; r < 4; ++r)
                acc[m][n][r] = __expf((acc[m][n][r] - 1.0f) * invT);
    #pragma unroll
    for (int m = 0; m < 8; ++m) {
        #pragma unroll
        for (int r = 0; r < 4; ++r) {
            float rp = 0.f;
            #pragma unroll
            for (int n = 0; n < 4; ++n) rp += acc[m][n][r];
            rp += __shfl_xor(rp, 1, 64);
            rp += __shfl_xor(rp, 2, 64);
            rp += __shfl_xor(rp, 4, 64);
            rp += __shfl_xor(rp, 8, 64);
            if (fr == 0) atomicAdd(&rs_l[wr * 128 + m * 16 + g * 4 + r], rp);
        }
    }
    #pragma unroll
    for (int n = 0; n < 4; ++n) {
        float cp = 0.f;
        #pragma unroll
        for (int m = 0; m < 8; ++m)
            #pragma unroll
            for (int r = 0; r < 4; ++r) cp += acc[m][n][r];
        cp += __shfl_xor(cp, 16, 64);
        cp += __shfl_xor(cp, 32, 64);
        if (g == 0) atomicAdd(&cs_l[wc * 64 + n * 16 + fr], cp);
    }
    __syncthreads();
    if (t < 256) {
        atomicAdd(&rs[rowBase + t], rs_l[t]);
        atomicAdd(&cs[colBase + t], cs_l[t]);
    }
}

// ---------------- final loss ----------------
__global__ __launch_bounds__(256) void final_kernel(
    const float* __restrict__ scal, const int* __restrict__ npart,
    const float* __restrict__ rs, const float* __restrict__ cs,
    const float* __restrict__ cntf, float* __restrict__ out)
{
    int t = threadIdx.x;
    float a = 0.0f, npl = 0.0f;
    for (int i = t; i < NB; i += 256) {
        float c = cntf[i];
        a += c * (logf(rs[i]) + logf(cs[i]));
        npl += c;
    }
    #pragma unroll
    for (int off = 32; off > 0; off >>= 1) {
        a += __shfl_down(a, off, 64);
        npl += __shfl_down(npl, off, 64);
    }
    __shared__ float ra[4], rn[4];
    int wid = t >> 6, lane = t & 63;
    if (lane == 0) { ra[wid] = a; rn[wid] = npl; }
    __syncthreads();
    if (t == 0) {
        float A  = ra[0] + ra[1] + ra[2] + ra[3];
        float np = rn[0] + rn[1] + rn[2] + rn[3];
        float invT = invT_from(scal[0], scal[1], scal[2], npart);
        float mf = scal[1];
        // lse_row[i] = 1/temp + log(rs[i]); v2t+t2v = sum cnt*(lse_r+lse_c) - 2*mf/temp
        float loss = (A + 2.0f * invT * (np - mf)) / (2.0f * np);
        out[0] = loss;
    }
}

extern "C" void kernel_launch(void* const* d_in, const int* in_sizes, int n_in,
                              void* d_out, int out_size, void* d_ws, size_t ws_size,
                              hipStream_t stream)
{
    const float* vf  = (const float*)d_in[0];
    const float* tf  = (const float*)d_in[1];
    const int*   ids = (const int*)d_in[2];

    float* ws_f = (float*)d_ws;
    float* scal = ws_f;                 // [0]=total [1]=S_mf [2]=trace [6]=grid-barrier counter
    float* rs   = ws_f + 16;            // 4096
    float* cs   = ws_f + 16 + 4096;     // 4096
    float* cntf = ws_f + 16 + 8192;     // 4096 (fully overwritten)
    int* npart  = (int*)(ws_f + 16 + 12288);   // 16 partial num_pos counts
    uint* bar   = (uint*)(scal + 6);           // zeroed by prep each call
    __hip_bfloat16* vhat  = (__hip_bfloat16*)((char*)d_ws + 65536);
    __hip_bfloat16* that_ = vhat + (size_t)NB * DD;

    // no memset: prep zeroes scal(+bar) and rs/cs; cntf/npart plain-stored

    prep_kernel<<<2096, 256, 0, stream>>>(vf, tf, ids, vhat, that_, cntf, npart, scal, rs);
    fused_kernel<<<NBLK, 512, 0, stream>>>(vhat, that_, ids, scal, rs, cs, npart, bar);
    final_kernel<<<1, 256, 0, stream>>>(scal, npart, rs, cs, cntf, (float*)d_out);
}

// Round 8
// 88.347 us; speedup vs baseline: 1.9482x; 1.1598x over previous
//
#include <hip/hip_runtime.h>
#include <hip/hip_bf16.h>

#define NB 4096
#define DD 768
#define NKT 24            // K-tiles of BK=32: 768/32
#define NBLK 256          // grid: 256 blocks = 1 per CU (128KB LDS forces 1/CU) -> all co-resident

typedef __bf16 bf16x8 __attribute__((ext_vector_type(8)));
typedef float f32x4 __attribute__((ext_vector_type(4)));
typedef unsigned int uint;

#define WAITVM(N) asm volatile("s_waitcnt vmcnt(" #N ")" ::: "memory")
#define WAITLGKM0 asm volatile("s_waitcnt lgkmcnt(0)" ::: "memory")

// ---------------- init: zero stats + grid-barrier counter (d_ws is poisoned 0xAA) ----------------
__global__ void init_kernel(float* scal)
{
    if (threadIdx.x < 16) scal[threadIdx.x] = 0.0f;
}

// ---------------- staging: one K-tile unit = A[256][32] + B[256][32] (32 KB) ----------------
// Swizzle (both sides, rule #21): logical chunk c (16B) of row r at phys chunk c ^ ((r>>1)&3).
// global_load_lds dest is linear (base+lane*16); lane's global source chunk = (lane&3)^((lane>>3)&3).
// Measured 0 bank conflicts (2-way aliasing = free, m136).
__device__ __forceinline__ void stage_range(
    __hip_bfloat16* ldsAll,
    const __hip_bfloat16* __restrict__ vhat, const __hip_bfloat16* __restrict__ that_,
    int rowBase, int colBase, int T, int i0, int i1, int wid, int lane)
{
    int u = T & 3;
    int k0 = T * 32;
    const __hip_bfloat16* src = (wid >= 4) ? that_ : vhat;
    int tb = (wid >= 4) ? colBase : rowBase;
    int w4 = wid & 3;
    int logc = (lane & 3) ^ ((lane >> 3) & 3);
    int rowIn = w4 * 64 + (lane >> 2);
    __hip_bfloat16* dbase = ldsAll + u * 16384 + ((wid >= 4) ? 8192 : 0) + w4 * 2048;
    #pragma unroll
    for (int i = i0; i <= i1; ++i) {
        const __hip_bfloat16* g = src + (size_t)(tb + rowIn + i * 16) * DD + k0 + logc * 8;
        __builtin_amdgcn_global_load_lds(
            (const __attribute__((address_space(1))) void*)g,
            (__attribute__((address_space(3))) void*)(dbase + i * 512),
            16, 0, 0);
    }
}

// ---------------- fully fused: normalize+cnt | bar1 | GEMM+stats | bar2 | exp sums | bar3 | loss ----------------
__global__ __launch_bounds__(512, 2) void fused_kernel(
    const float* __restrict__ vf, const float* __restrict__ tf, const int* __restrict__ ids,
    __hip_bfloat16* __restrict__ vhat, __hip_bfloat16* __restrict__ that_,
    float* scal, float* rs, float* cs, float* cntf, int* npart, uint* bar,
    float* __restrict__ out)
{
    __shared__ __hip_bfloat16 ldsAll[4 * 16384];   // 128 KB: ring units; reused as ids stage in phase 0
    __shared__ int idr[256], idc[256];
    __shared__ float red[24];
    __shared__ float rs_l[256], cs_l[256];
    __shared__ int bp[16], wred_i[8];
    __shared__ float ra[8], rn[8];
    __shared__ float invT_sh, mf_sh;

    int rawb = blockIdx.x;
    int t = threadIdx.x, wid = t >> 6, lane = t & 63;

    // ===== phase 0a: normalize 32 rows (1 wave = 1 row, float4 loads) =====
    #pragma unroll
    for (int it = 0; it < 4; ++it) {
        int row = rawb * 32 + wid * 4 + it;
        const float* src;
        __hip_bfloat16* dst;
        if (row < NB) { src = vf + (size_t)row * DD; dst = vhat + (size_t)row * DD; }
        else          { src = tf + (size_t)(row - NB) * DD; dst = that_ + (size_t)(row - NB) * DD; }
        float4 x0 = *(const float4*)(src + lane * 4);
        float4 x1 = *(const float4*)(src + 256 + lane * 4);
        float4 x2 = *(const float4*)(src + 512 + lane * 4);
        float s = x0.x*x0.x + x0.y*x0.y + x0.z*x0.z + x0.w*x0.w
                + x1.x*x1.x + x1.y*x1.y + x1.z*x1.z + x1.w*x1.w
                + x2.x*x2.x + x2.y*x2.y + x2.z*x2.z + x2.w*x2.w;
        #pragma unroll
        for (int off = 1; off < 64; off <<= 1) s += __shfl_xor(s, off, 64);
        float scale = 1.0f / sqrtf(s);
        unsigned short* dsh = (unsigned short*)dst;
        ushort4 o0, o1, o2;
        o0.x = __builtin_bit_cast(unsigned short, __float2bfloat16(x0.x * scale));
        o0.y = __builtin_bit_cast(unsigned short, __float2bfloat16(x0.y * scale));
        o0.z = __builtin_bit_cast(unsigned short, __float2bfloat16(x0.z * scale));
        o0.w = __builtin_bit_cast(unsigned short, __float2bfloat16(x0.w * scale));
        o1.x = __builtin_bit_cast(unsigned short, __float2bfloat16(x1.x * scale));
        o1.y = __builtin_bit_cast(unsigned short, __float2bfloat16(x1.y * scale));
        o1.z = __builtin_bit_cast(unsigned short, __float2bfloat16(x1.z * scale));
        o1.w = __builtin_bit_cast(unsigned short, __float2bfloat16(x1.w * scale));
        o2.x = __builtin_bit_cast(unsigned short, __float2bfloat16(x2.x * scale));
        o2.y = __builtin_bit_cast(unsigned short, __float2bfloat16(x2.y * scale));
        o2.z = __builtin_bit_cast(unsigned short, __float2bfloat16(x2.z * scale));
        o2.w = __builtin_bit_cast(unsigned short, __float2bfloat16(x2.w * scale));
        *(ushort4*)(dsh + lane * 4)       = o0;
        *(ushort4*)(dsh + 256 + lane * 4) = o1;
        *(ushort4*)(dsh + 512 + lane * 4) = o2;
    }

    // ===== phase 0b: cnt — ids staged into ldsAll; 32 lanes per id =====
    int* idsh = (int*)ldsAll;
    for (int i = t; i < NB; i += 512) idsh[i] = ids[i];
    __syncthreads();
    {
        int sub = t >> 5, l32 = t & 31;
        int my = idsh[rawb * 16 + sub];
        int c = 0;
        #pragma unroll 16
        for (int j = l32; j < NB; j += 32) c += (idsh[j] == my);
        #pragma unroll
        for (int off = 16; off > 0; off >>= 1) c += __shfl_down(c, off, 32);
        if (l32 == 0) { cntf[rawb * 16 + sub] = (float)c; bp[sub] = c; }
    }
    // ===== phase 0c: zero rs+cs (contiguous 8192 floats starting at rs) =====
    if (t < 32) rs[rawb * 32 + t] = 0.0f;
    __syncthreads();
    if (t == 0) {
        int s = 0;
        #pragma unroll
        for (int i = 0; i < 16; ++i) s += bp[i];
        npart[rawb] = s;
    }

    // ===== grid barrier #1: vhat/that/cntf/npart/rs-zero published =====
    __syncthreads();
    if (t == 0) {
        __hip_atomic_fetch_add(bar, 1u, __ATOMIC_ACQ_REL, __HIP_MEMORY_SCOPE_AGENT);
        while (__hip_atomic_load(bar, __ATOMIC_ACQUIRE, __HIP_MEMORY_SCOPE_AGENT) < NBLK)
            __builtin_amdgcn_s_sleep(2);
    }
    __syncthreads();

    // ===== GEMM: 256x256 tile, 8 waves, BK=32, 4-deep ring =====
    // XCD-chunked bijective swizzle: 8 regions of 4by x 8bx (grid 256 = 16x16)
    int rg = rawb & 7, sq = rawb >> 3;
    int by = (rg >> 1) * 4 + (sq >> 3);
    int bx = (rg & 1) * 8 + (sq & 7);
    int rowBase = by * 256, colBase = bx * 256;
    int wr = wid >> 2, wc = wid & 3;
    int fr = lane & 15, g = lane >> 4;

    f32x4 acc[8][4];
    #pragma unroll
    for (int m = 0; m < 8; ++m)
        #pragma unroll
        for (int n = 0; n < 4; ++n) acc[m][n] = (f32x4){0.f, 0.f, 0.f, 0.f};

    int pcoff = ((g ^ ((fr >> 1) & 3)) * 8);
    int aoff = (wr * 128 + fr) * 32 + pcoff;
    int boff = 8192 + (wc * 64 + fr) * 32 + pcoff;

    stage_range(ldsAll, vhat, that_, rowBase, colBase, 0, 0, 3, wid, lane);
    stage_range(ldsAll, vhat, that_, rowBase, colBase, 1, 0, 3, wid, lane);
    stage_range(ldsAll, vhat, that_, rowBase, colBase, 2, 0, 3, wid, lane);
    WAITVM(8);
    __builtin_amdgcn_s_barrier();

    for (int T = 0; T < NKT; ++T) {
        const __hip_bfloat16* U = ldsAll + (T & 3) * 16384;
        // phase A: reads(a0,bb) || stage half1(T+3) -> BAR -> MFMA m0..3
        bf16x8 a0[4], bb[4];
        #pragma unroll
        for (int m = 0; m < 4; ++m) a0[m] = *(const bf16x8*)(U + aoff + m * 512);
        #pragma unroll
        for (int n = 0; n < 4; ++n) bb[n] = *(const bf16x8*)(U + boff + n * 512);
        if (T + 3 < NKT)
            stage_range(ldsAll, vhat, that_, rowBase, colBase, T + 3, 0, 1, wid, lane);
        __builtin_amdgcn_sched_barrier(0);
        __builtin_amdgcn_s_barrier();
        WAITLGKM0;
        __builtin_amdgcn_sched_barrier(0);
        __builtin_amdgcn_s_setprio(1);
        #pragma unroll
        for (int m = 0; m < 4; ++m)
            #pragma unroll
            for (int n = 0; n < 4; ++n)
                acc[m][n] = __builtin_amdgcn_mfma_f32_16x16x32_bf16(a0[m], bb[n], acc[m][n], 0, 0, 0);
        __builtin_amdgcn_s_setprio(0);
        __builtin_amdgcn_sched_barrier(0);
        __builtin_amdgcn_s_barrier();
        // phase B: reads(a1) || stage half2(T+3) -> BAR -> MFMA m4..7
        bf16x8 a1[4];
        #pragma unroll
        for (int m = 0; m < 4; ++m) a1[m] = *(const bf16x8*)(U + aoff + (m + 4) * 512);
        if (T + 3 < NKT)
            stage_range(ldsAll, vhat, that_, rowBase, colBase, T + 3, 2, 3, wid, lane);
        __builtin_amdgcn_sched_barrier(0);
        __builtin_amdgcn_s_barrier();
        WAITLGKM0;
        __builtin_amdgcn_sched_barrier(0);
        __builtin_amdgcn_s_setprio(1);
        #pragma unroll
        for (int m = 0; m < 4; ++m)
            #pragma unroll
            for (int n = 0; n < 4; ++n)
                acc[m + 4][n] = __builtin_amdgcn_mfma_f32_16x16x32_bf16(a1[m], bb[n], acc[m + 4][n], 0, 0, 0);
        __builtin_amdgcn_s_setprio(0);
        __builtin_amdgcn_sched_barrier(0);
        // tile boundary: T+1 staged; keep T+2/T+3 in flight (never vmcnt 0 mid-loop)
        if (T < NKT - 3)       { WAITVM(8); }
        else if (T == NKT - 3) { WAITVM(4); }
        else if (T == NKT - 2) { WAITVM(0); }
        __builtin_amdgcn_s_barrier();
    }

    // ===== stats: {total, S_mf, trace};  C/D: col=fr, row=g*4+reg [m89-verified] =====
    if (t < 256) idr[t] = ids[rowBase + t];
    else         idc[t - 256] = ids[colBase + (t - 256)];
    __syncthreads();
    {
        float tsum = 0.f, msum = 0.f, dsum = 0.f;
        #pragma unroll
        for (int m = 0; m < 8; ++m) {
            int rl = wr * 128 + m * 16 + g * 4;
            #pragma unroll
            for (int n = 0; n < 4; ++n) {
                int cl = wc * 64 + n * 16 + fr;
                int colId = idc[cl];
                int gj = colBase + cl;
                #pragma unroll
                for (int r = 0; r < 4; ++r) {
                    float val = acc[m][n][r];
                    tsum += val;
                    if (idr[rl + r] == colId) msum += val;
                    if (rowBase + rl + r == gj) dsum += val;
                }
            }
        }
        #pragma unroll
        for (int off = 32; off > 0; off >>= 1) {
            tsum += __shfl_down(tsum, off, 64);
            msum += __shfl_down(msum, off, 64);
            dsum += __shfl_down(dsum, off, 64);
        }
        if (lane == 0) { red[wid] = tsum; red[8 + wid] = msum; red[16 + wid] = dsum; }
        __syncthreads();
        if (t == 0) {
            float s0 = 0.f, s1 = 0.f, s2 = 0.f;
            #pragma unroll
            for (int w = 0; w < 8; ++w) { s0 += red[w]; s1 += red[8 + w]; s2 += red[16 + w]; }
            atomicAdd(&scal[0], s0);
            atomicAdd(&scal[1], s1);
            atomicAdd(&scal[2], s2);
        }
    }

    // ===== grid barrier #2: stats complete =====
    __syncthreads();
    if (t == 0) {
        __hip_atomic_fetch_add(bar, 1u, __ATOMIC_ACQ_REL, __HIP_MEMORY_SCOPE_AGENT);
        while (__hip_atomic_load(bar, __ATOMIC_ACQUIRE, __HIP_MEMORY_SCOPE_AGENT) < 2 * NBLK)
            __builtin_amdgcn_s_sleep(2);
    }
    __syncthreads();

    // ===== np reduce + invT (all blocks need it) =====
    {
        int myn = (t < NBLK) ? npart[t] : 0;
        #pragma unroll
        for (int off = 32; off > 0; off >>= 1) myn += __shfl_down(myn, off, 64);
        if (lane == 0) wred_i[wid] = myn;
        __syncthreads();
        if (t == 0) {
            int npi = 0;
            #pragma unroll
            for (int w = 0; w < 8; ++w) npi += wred_i[w];
            float total = __hip_atomic_load(&scal[0], __ATOMIC_RELAXED, __HIP_MEMORY_SCOPE_AGENT);
            float mf    = __hip_atomic_load(&scal[1], __ATOMIC_RELAXED, __HIP_MEMORY_SCOPE_AGENT);
            float trace = __hip_atomic_load(&scal[2], __ATOMIC_RELAXED, __HIP_MEMORY_SCOPE_AGENT);
            float np = (float)npi;
            float pos_cnt = np - (float)NB;
            float neg_cnt = (float)NB * (float)NB - np;
            float pos_mean = (mf - trace) / fmaxf(1.0f, pos_cnt);
            float neg_mean = (total - mf) / fmaxf(1.0f, neg_cnt);
            float sep = pos_mean - neg_mean;
            float temp = 0.07f * (0.8f + 0.4f * expf(-2.0f * sep));
            temp = fminf(fmaxf(temp, 0.04f), 0.2f);
            invT_sh = 1.0f / temp;
            mf_sh = mf;
        }
        if (t < 256) { rs_l[t] = 0.0f; cs_l[t] = 0.0f; }
        __syncthreads();
    }
    float invT = invT_sh;

    // ===== exp((sim-1)/temp) row & col sums straight from registers =====
    #pragma unroll
    for (int m = 0; m < 8; ++m)
        #pragma unroll
        for (int n = 0; n < 4; ++n)
            #pragma unroll
            for (int r = 0; r < 4; ++r)
                acc[m][n][r] = __expf((acc[m][n][r] - 1.0f) * invT);
    #pragma unroll
    for (int m = 0; m < 8; ++m) {
        #pragma unroll
        for (int r = 0; r < 4; ++r) {
            float rp = 0.f;
            #pragma unroll
            for (int n = 0; n < 4; ++n) rp += acc[m][n][r];
            rp += __shfl_xor(rp, 1, 64);
            rp += __shfl_xor(rp, 2, 64);
            rp += __shfl_xor(rp, 4, 64);
            rp += __shfl_xor(rp, 8, 64);
            if (fr == 0) atomicAdd(&rs_l[wr * 128 + m * 16 + g * 4 + r], rp);
        }
    }
    #pragma unroll
    for (int n = 0; n < 4; ++n) {
        float cp = 0.f;
        #pragma unroll
        for (int m = 0; m < 8; ++m)
            #pragma unroll
            for (int r = 0; r < 4; ++r) cp += acc[m][n][r];
        cp += __shfl_xor(cp, 16, 64);
        cp += __shfl_xor(cp, 32, 64);
        if (g == 0) atomicAdd(&cs_l[wc * 64 + n * 16 + fr], cp);
    }
    __syncthreads();
    if (t < 256) {
        atomicAdd(&rs[rowBase + t], rs_l[t]);
        atomicAdd(&cs[colBase + t], cs_l[t]);
    }

    // ===== barrier #3: all arrive; only block 0 spins and finishes =====
    __syncthreads();
    if (t == 0)
        __hip_atomic_fetch_add(bar, 1u, __ATOMIC_ACQ_REL, __HIP_MEMORY_SCOPE_AGENT);
    if (rawb != 0) return;
    if (t == 0) {
        while (__hip_atomic_load(bar, __ATOMIC_ACQUIRE, __HIP_MEMORY_SCOPE_AGENT) < 3 * NBLK)
            __builtin_amdgcn_s_sleep(2);
    }
    __syncthreads();

    // ===== final loss (block 0, 512 threads) =====
    {
        float a = 0.f, npl = 0.f;
        for (int i = t; i < NB; i += 512) {
            float cf = cntf[i];
            a += cf * (logf(rs[i]) + logf(cs[i]));
            npl += cf;
        }
        #pragma unroll
        for (int off = 32; off > 0; off >>= 1) {
            a += __shfl_down(a, off, 64);
            npl += __shfl_down(npl, off, 64);
        }
        if (lane == 0) { ra[wid] = a; rn[wid] = npl; }
        __syncthreads();
        if (t == 0) {
            float A = 0.f, np = 0.f;
            #pragma unroll
            for (int w = 0; w < 8; ++w) { A += ra[w]; np += rn[w]; }
            // lse_row[i] = 1/temp + log(rs[i]); v2t+t2v = sum cnt*(lse_r+lse_c) - 2*mf/temp
            out[0] = (A + 2.0f * invT_sh * (np - mf_sh)) / (2.0f * np);
        }
    }
}

extern "C" void kernel_launch(void* const* d_in, const int* in_sizes, int n_in,
                              void* d_out, int out_size, void* d_ws, size_t ws_size,
                              hipStream_t stream)
{
    const float* vf  = (const float*)d_in[0];
    const float* tf  = (const float*)d_in[1];
    const int*   ids = (const int*)d_in[2];

    float* ws_f = (float*)d_ws;
    float* scal = ws_f;                 // [0]=total [1]=S_mf [2]=trace [6]=bar
    float* rs   = ws_f + 16;            // 4096  (cs contiguous after rs — fused zeroes both via rs)
    float* cs   = ws_f + 16 + 4096;     // 4096
    float* cntf = ws_f + 16 + 8192;     // 4096
    int* npart  = (int*)(ws_f + 16 + 12288);   // 256 partial num_pos counts
    uint* bar   = (uint*)(scal + 6);
    __hip_bfloat16* vhat  = (__hip_bfloat16*)((char*)d_ws + 131072);
    __hip_bfloat16* that_ = vhat + (size_t)NB * DD;

    init_kernel<<<1, 64, 0, stream>>>(scal);
    fused_kernel<<<NBLK, 512, 0, stream>>>(vf, tf, ids, vhat, that_,
                                           scal, rs, cs, cntf, npart, bar, (float*)d_out);
}